// Round 13
// baseline (197.661 us; speedup 1.0000x reference)
//
#include <hip/hip_runtime.h>
#include <hip/hip_bf16.h>
#include <hip/hip_fp16.h>
#include <cstdint>
#include <cstddef>

#define NB 2
#define NTOK 12096
#define TOKS (NB * NTOK)   // 24192
#define DIMC 384
#define NHEADS 6
#define CHD 64

typedef __attribute__((ext_vector_type(8))) __bf16 bf16x8;
typedef __attribute__((ext_vector_type(4))) float f32x4;

__device__ __forceinline__ float wave_reduce_add(float v) {
#pragma unroll
  for (int o = 32; o > 0; o >>= 1) v += __shfl_xor(v, o, 64);
  return v;
}

__device__ __forceinline__ float bf_lo(uint u) {
  union { uint i; float f; } c; c.i = u << 16; return c.f;
}
__device__ __forceinline__ float bf_hi(uint u) {
  union { uint i; float f; } c; c.i = u & 0xffff0000u; return c.f;
}
__device__ __forceinline__ ushort f2bf(float x) {
  union { __hip_bfloat16 b; ushort u; } c; c.b = __float2bfloat16(x); return c.u;
}

// bijective XCD-chunked id mapping: 8 contiguous chunks, chunk i on XCD i
__device__ __forceinline__ int xcd_chunk(int bid, int nwg) {
  int xcd = bid & 7, off = bid >> 3;
  int q = nwg >> 3, r = nwg & 7;
  return (xcd < r ? xcd * (q + 1) : r * (q + 1) + (xcd - r) * q) + off;
}

// async global->LDS, 16B per lane; LDS dest is wave-uniform base + lane*16
__device__ __forceinline__ void gload16(const ushort* g, ushort* l) {
  __builtin_amdgcn_global_load_lds(
      (const __attribute__((address_space(1))) uint*)g,
      (__attribute__((address_space(3))) uint*)l, 16, 0, 0);
}

// ---------------------------------------------------------------------------
// Prelude: blocks 0..575 convert weights (fp32 [K][N] -> bf16 [Np][K] + padded
// biases; fc1 gets ffn_norm weight FOLDED IN: fc1t[n][k] = ffw[k]*fc1[k][n]).
// Block 0 also computes the LN-fold vectors fcs/fcc. Blocks 576.. run the
// fused LN3 (q build + qn/aq/af).
// ---------------------------------------------------------------------------
__global__ __launch_bounds__(256) void prelude_kernel(
    const float* __restrict__ Wv, const float* __restrict__ Woff,
    const float* __restrict__ Watt, const float* __restrict__ Wo,
    const float* __restrict__ fc1, const float* __restrict__ fc2,
    const float* __restrict__ boff, const float* __restrict__ batt,
    const float* __restrict__ fc1b, const float* __restrict__ ffw,
    const float* __restrict__ ffb,
    __hip_bfloat16* __restrict__ Wvt, __hip_bfloat16* __restrict__ Wot,
    __hip_bfloat16* __restrict__ Wofat, __hip_bfloat16* __restrict__ fc1t,
    __hip_bfloat16* __restrict__ fc2t, float* __restrict__ bofat,
    float* __restrict__ fcs, float* __restrict__ fcc,
    const float* __restrict__ query, const float* __restrict__ feat,
    const float* __restrict__ w1, const float* __restrict__ b1,
    const float* __restrict__ w2, const float* __restrict__ b2,
    const float* __restrict__ w3, const float* __restrict__ b3,
    const float* __restrict__ w4, const float* __restrict__ b4,
    __hip_bfloat16* __restrict__ qn, __hip_bfloat16* __restrict__ aq,
    __hip_bfloat16* __restrict__ af) {
  if (blockIdx.x < 576) {
    int id = blockIdx.x * 256 + threadIdx.x;
    int k = id % 384, n = id / 384;
    Wvt[(size_t)n * 384 + k] = __float2bfloat16(Wv[(size_t)k * 384 + n]);
    Wot[(size_t)n * 384 + k] = __float2bfloat16(Wo[(size_t)k * 384 + n]);
    if (n < 256) {
      float v = 0.f;
      if (n < 144) v = Woff[(size_t)k * 144 + n];
      else if (n < 216) v = Watt[(size_t)k * 72 + (n - 144)];
      Wofat[(size_t)n * 384 + k] = __float2bfloat16(v);
    }
    if (n < 128)
      fc1t[(size_t)n * 384 + k] =
          __float2bfloat16(n < 96 ? ffw[k] * fc1[(size_t)k * 96 + n] : 0.f);
    if (k < 96)
      fc2t[(size_t)n * 96 + k] = __float2bfloat16(fc2[(size_t)k * 384 + n]);
    if (id < 256) bofat[id] = id < 144 ? boff[id] : (id < 216 ? batt[id - 144] : 0.f);
    // LN-fold vectors: fcs[n] = sum_k ffw_k*fc1[k][n];
    // fcc[n] = sum_k ffb_k*fc1[k][n] + fc1b[n]
    if (blockIdx.x == 0 && threadIdx.x < 128) {
      int n = threadIdx.x;
      float s = 0.f, c = 0.f;
      if (n < 96) {
        for (int kk = 0; kk < 384; ++kk) {
          float w = fc1[(size_t)kk * 96 + n];
          s += ffw[kk] * w;
          c += ffb[kk] * w;
        }
        c += fc1b[n];
      }
      fcs[n] = s;
      fcc[n] = c;
    }
    return;
  }

  int wid = ((blockIdx.x - 576) * blockDim.x + threadIdx.x) >> 6;
  if (wid >= TOKS) return;
  int lane = threadIdx.x & 63;
  int bb = wid / NTOK;
  int nq = wid - bb * NTOK;

  float x[6];
  const float* qp = query + (size_t)wid * DIMC + lane;
#pragma unroll
  for (int i = 0; i < 6; ++i) x[i] = qp[64 * i];
  if (nq >= 9216 && nq < 11520) {
    const float* fp = feat + ((size_t)bb * 2304 + (nq - 9216)) * DIMC + lane;
#pragma unroll
    for (int i = 0; i < 6; ++i) x[i] += fp[64 * i];
  }

  float s = 0.f, ss = 0.f;
#pragma unroll
  for (int i = 0; i < 6; ++i) { s += x[i]; ss += x[i] * x[i]; }
  s = wave_reduce_add(s); ss = wave_reduce_add(ss);
  float mean = s * (1.f / DIMC);
  float rs = rsqrtf(ss * (1.f / DIMC) - mean * mean + 1e-6f);

  float qv[6], fv[6];
  __hip_bfloat16* qnp = qn + (size_t)wid * DIMC + lane;
#pragma unroll
  for (int i = 0; i < 6; ++i) {
    int e = lane + 64 * i;
    float xh = (x[i] - mean) * rs;
    qv[i] = xh * w1[e] + b1[e];
    fv[i] = xh * w2[e] + b2[e];
    qnp[64 * i] = __float2bfloat16(qv[i]);
  }

  s = 0.f; ss = 0.f;
#pragma unroll
  for (int i = 0; i < 6; ++i) { s += qv[i]; ss += qv[i] * qv[i]; }
  s = wave_reduce_add(s); ss = wave_reduce_add(ss);
  float m2 = s * (1.f / DIMC);
  float rs2 = rsqrtf(ss * (1.f / DIMC) - m2 * m2 + 1e-6f);
  __hip_bfloat16* aqp = aq + (size_t)wid * DIMC + lane;
#pragma unroll
  for (int i = 0; i < 6; ++i) {
    int e = lane + 64 * i;
    aqp[64 * i] = __float2bfloat16((qv[i] - m2) * rs2 * w3[e] + b3[e]);
  }

  s = 0.f; ss = 0.f;
#pragma unroll
  for (int i = 0; i < 6; ++i) { s += fv[i]; ss += fv[i] * fv[i]; }
  s = wave_reduce_add(s); ss = wave_reduce_add(ss);
  float m3 = s * (1.f / DIMC);
  float rs3 = rsqrtf(ss * (1.f / DIMC) - m3 * m3 + 1e-6f);
  __hip_bfloat16* afp = af + (size_t)wid * DIMC + lane;
#pragma unroll
  for (int i = 0; i < 6; ++i) {
    int e = lane + 64 * i;
    afp[64 * i] = __float2bfloat16((fv[i] - m3) * rs3 * w4[e] + b4[e]);
  }
}

// ---------------------------------------------------------------------------
// Generic bf16 MFMA GEMM (used for fc2): 128x128 tile, 4 waves, 2-phase
// double-buffered global_load_lds pipeline, pre-swizzled source, XCD-chunked.
// EPI 2: +bias += C(f32).
// ---------------------------------------------------------------------------
template <int EPI, int OUTBF16>
__global__ __launch_bounds__(256) void gemm_mfma(
    const __hip_bfloat16* __restrict__ A, const __hip_bfloat16* __restrict__ Wt,
    const float* __restrict__ bias, const void* __restrict__ Rv,
    void* __restrict__ Cv, int K, int Np, int ntx) {
  __shared__ __align__(16) ushort As[2 * 128 * 32];
  __shared__ __align__(16) ushort Bs[2 * 128 * 32];
  const int tid = threadIdx.x;
  const int tile = xcd_chunk(blockIdx.x, gridDim.x);
  const int tx = tile % ntx, ty = tile / ntx;
  const int m0 = ty * 128, n0 = tx * 128;

  const int lane = tid & 63, wv = tid >> 6;
  const int wm = (wv >> 1) * 64, wn = (wv & 1) * 64;
  const int rl = lane & 15, kb = lane >> 4;

  const int c0 = wv * 64 + lane;
  const int c1 = c0 + 256;
  const int r0c = c0 >> 2, b0 = (c0 & 3) ^ (r0c & 3);
  const int r1c = c1 >> 2, b1 = (c1 & 3) ^ (r1c & 3);
  const ushort* gA0 = (const ushort*)A + (size_t)(m0 + r0c) * K + b0 * 8;
  const ushort* gA1 = (const ushort*)A + (size_t)(m0 + r1c) * K + b1 * 8;
  const ushort* gB0 = (const ushort*)Wt + (size_t)(n0 + r0c) * K + b0 * 8;
  const ushort* gB1 = (const ushort*)Wt + (size_t)(n0 + r1c) * K + b1 * 8;
  ushort* lA0 = &As[(size_t)wv * 512];
  ushort* lA1 = &As[(size_t)wv * 512 + 2048];
  ushort* lB0 = &Bs[(size_t)wv * 512];
  ushort* lB1 = &Bs[(size_t)wv * 512 + 2048];

  f32x4 acc[4][4] = {};
  const int nt = K >> 5;

  gload16(gA0, lA0);
  gload16(gA1, lA1);
  gload16(gB0, lB0);
  gload16(gB1, lB1);
  __syncthreads();

  for (int t = 0; t < nt; ++t) {
    const int cb = (t & 1) << 12;
    const int nb = 4096 - cb;
    if (t + 1 < nt) {
      const int k1 = (t + 1) << 5;
      gload16(gA0 + k1, lA0 + nb);
      gload16(gA1 + k1, lA1 + nb);
      gload16(gB0 + k1, lB0 + nb);
      gload16(gB1 + k1, lB1 + nb);
    }
    bf16x8 avf[4], bvf[4];
#pragma unroll
    for (int i = 0; i < 4; ++i) {
      int ra = wm + i * 16 + rl;
      avf[i] = *(const bf16x8*)&As[cb + ra * 32 + ((kb ^ (ra & 3)) << 3)];
      int rb = wn + i * 16 + rl;
      bvf[i] = *(const bf16x8*)&Bs[cb + rb * 32 + ((kb ^ (rb & 3)) << 3)];
    }
#pragma unroll
    for (int i = 0; i < 4; ++i)
#pragma unroll
      for (int j = 0; j < 4; ++j)
        acc[i][j] = __builtin_amdgcn_mfma_f32_16x16x32_bf16(avf[i], bvf[j],
                                                            acc[i][j], 0, 0, 0);
    __syncthreads();
  }

#pragma unroll
  for (int i = 0; i < 4; ++i) {
#pragma unroll
    for (int j = 0; j < 4; ++j) {
      int col = n0 + wn + j * 16 + rl;
      float bsv = bias[col];
#pragma unroll
      for (int rr = 0; rr < 4; ++rr) {
        int row = m0 + wm + i * 16 + kb * 4 + rr;
        size_t o = (size_t)row * Np + col;
        float v = acc[i][j][rr] + bsv;
        if (EPI == 1) v += __bfloat162float(((const __hip_bfloat16*)Rv)[o]);
        if (EPI == 2) v += ((const float*)Cv)[o];
        if (OUTBF16) ((__hip_bfloat16*)Cv)[o] = __float2bfloat16(v);
        else ((float*)Cv)[o] = v;
      }
    }
  }
}

// ---------------------------------------------------------------------------
// Wout GEMM: out = samp @ Wot + bo + qn (f32), plus bf16 copy outbf, plus
// per-token LN stats (sum, sumsq) accumulated via shfl reduce + atomics.
// K=384, Np=384, ntx=3, grid 567.
// ---------------------------------------------------------------------------
__global__ __launch_bounds__(256) void gemm_wout(
    const __hip_bfloat16* __restrict__ A, const __hip_bfloat16* __restrict__ Wt,
    const float* __restrict__ bias, const __hip_bfloat16* __restrict__ Rv,
    float* __restrict__ out, __hip_bfloat16* __restrict__ outbf,
    float* __restrict__ stats) {
  __shared__ __align__(16) ushort As[2 * 128 * 32];
  __shared__ __align__(16) ushort Bs[2 * 128 * 32];
  const int K = 384, Np = 384, ntx = 3;
  const int tid = threadIdx.x;
  const int tile = xcd_chunk(blockIdx.x, gridDim.x);
  const int tx = tile % ntx, ty = tile / ntx;
  const int m0 = ty * 128, n0 = tx * 128;

  const int lane = tid & 63, wv = tid >> 6;
  const int wm = (wv >> 1) * 64, wn = (wv & 1) * 64;
  const int rl = lane & 15, kb = lane >> 4;

  const int c0 = wv * 64 + lane;
  const int c1 = c0 + 256;
  const int r0c = c0 >> 2, b0 = (c0 & 3) ^ (r0c & 3);
  const int r1c = c1 >> 2, b1 = (c1 & 3) ^ (r1c & 3);
  const ushort* gA0 = (const ushort*)A + (size_t)(m0 + r0c) * K + b0 * 8;
  const ushort* gA1 = (const ushort*)A + (size_t)(m0 + r1c) * K + b1 * 8;
  const ushort* gB0 = (const ushort*)Wt + (size_t)(n0 + r0c) * K + b0 * 8;
  const ushort* gB1 = (const ushort*)Wt + (size_t)(n0 + r1c) * K + b1 * 8;
  ushort* lA0 = &As[(size_t)wv * 512];
  ushort* lA1 = &As[(size_t)wv * 512 + 2048];
  ushort* lB0 = &Bs[(size_t)wv * 512];
  ushort* lB1 = &Bs[(size_t)wv * 512 + 2048];

  f32x4 acc[4][4] = {};
  const int nt = K >> 5;

  gload16(gA0, lA0);
  gload16(gA1, lA1);
  gload16(gB0, lB0);
  gload16(gB1, lB1);
  __syncthreads();

  for (int t = 0; t < nt; ++t) {
    const int cb = (t & 1) << 12;
    const int nb = 4096 - cb;
    if (t + 1 < nt) {
      const int k1 = (t + 1) << 5;
      gload16(gA0 + k1, lA0 + nb);
      gload16(gA1 + k1, lA1 + nb);
      gload16(gB0 + k1, lB0 + nb);
      gload16(gB1 + k1, lB1 + nb);
    }
    bf16x8 avf[4], bvf[4];
#pragma unroll
    for (int i = 0; i < 4; ++i) {
      int ra = wm + i * 16 + rl;
      avf[i] = *(const bf16x8*)&As[cb + ra * 32 + ((kb ^ (ra & 3)) << 3)];
      int rb = wn + i * 16 + rl;
      bvf[i] = *(const bf16x8*)&Bs[cb + rb * 32 + ((kb ^ (rb & 3)) << 3)];
    }
#pragma unroll
    for (int i = 0; i < 4; ++i)
#pragma unroll
      for (int j = 0; j < 4; ++j)
        acc[i][j] = __builtin_amdgcn_mfma_f32_16x16x32_bf16(avf[i], bvf[j],
                                                            acc[i][j], 0, 0, 0);
    __syncthreads();
  }

  float s1a[4][4] = {}, s2a[4][4] = {};
#pragma unroll
  for (int i = 0; i < 4; ++i) {
#pragma unroll
    for (int j = 0; j < 4; ++j) {
      int col = n0 + wn + j * 16 + rl;
      float bsv = bias[col];
#pragma unroll
      for (int rr = 0; rr < 4; ++rr) {
        int row = m0 + wm + i * 16 + kb * 4 + rr;
        size_t o = (size_t)row * Np + col;
        float v = acc[i][j][rr] + bsv +
                  __bfloat162float(Rv[o]);
        out[o] = v;
        outbf[o] = __float2bfloat16(v);
        s1a[i][rr] += v;
        s2a[i][rr] += v * v;
      }
    }
  }
  // reduce each row's 64-col partial across the 16 rl lanes, then atomics
#pragma unroll
  for (int i = 0; i < 4; ++i) {
#pragma unroll
    for (int rr = 0; rr < 4; ++rr) {
      float a = s1a[i][rr], bq = s2a[i][rr];
      a += __shfl_xor(a, 1, 64);  bq += __shfl_xor(bq, 1, 64);
      a += __shfl_xor(a, 2, 64);  bq += __shfl_xor(bq, 2, 64);
      a += __shfl_xor(a, 4, 64);  bq += __shfl_xor(bq, 4, 64);
      a += __shfl_xor(a, 8, 64);  bq += __shfl_xor(bq, 8, 64);
      if (rl == 0) {
        int row = m0 + wm + i * 16 + kb * 4 + rr;
        atomicAdd(&stats[row * 2 + 0], a);
        atomicAdd(&stats[row * 2 + 1], bq);
      }
    }
  }
}

// ---------------------------------------------------------------------------
// fc1 GEMM with LN folded: h1 = r*(outbf @ fc1t' - mu*fcs) + fcc, bf16 out.
// K=384, Np=128, ntx=1, grid 189. r,mu from stats (per-token sum/sumsq).
// ---------------------------------------------------------------------------
__global__ __launch_bounds__(256) void gemm_fc1(
    const __hip_bfloat16* __restrict__ A, const __hip_bfloat16* __restrict__ Wt,
    const float* __restrict__ stats, const float* __restrict__ fcs,
    const float* __restrict__ fcc, __hip_bfloat16* __restrict__ C) {
  __shared__ __align__(16) ushort As[2 * 128 * 32];
  __shared__ __align__(16) ushort Bs[2 * 128 * 32];
  const int K = 384, Np = 128;
  const int tid = threadIdx.x;
  const int tile = xcd_chunk(blockIdx.x, gridDim.x);
  const int m0 = tile * 128, n0 = 0;

  const int lane = tid & 63, wv = tid >> 6;
  const int wm = (wv >> 1) * 64, wn = (wv & 1) * 64;
  const int rl = lane & 15, kb = lane >> 4;

  const int c0 = wv * 64 + lane;
  const int c1 = c0 + 256;
  const int r0c = c0 >> 2, b0 = (c0 & 3) ^ (r0c & 3);
  const int r1c = c1 >> 2, b1 = (c1 & 3) ^ (r1c & 3);
  const ushort* gA0 = (const ushort*)A + (size_t)(m0 + r0c) * K + b0 * 8;
  const ushort* gA1 = (const ushort*)A + (size_t)(m0 + r1c) * K + b1 * 8;
  const ushort* gB0 = (const ushort*)Wt + (size_t)(n0 + r0c) * K + b0 * 8;
  const ushort* gB1 = (const ushort*)Wt + (size_t)(n0 + r1c) * K + b1 * 8;
  ushort* lA0 = &As[(size_t)wv * 512];
  ushort* lA1 = &As[(size_t)wv * 512 + 2048];
  ushort* lB0 = &Bs[(size_t)wv * 512];
  ushort* lB1 = &Bs[(size_t)wv * 512 + 2048];

  f32x4 acc[4][4] = {};
  const int nt = K >> 5;

  gload16(gA0, lA0);
  gload16(gA1, lA1);
  gload16(gB0, lB0);
  gload16(gB1, lB1);
  __syncthreads();

  for (int t = 0; t < nt; ++t) {
    const int cb = (t & 1) << 12;
    const int nb = 4096 - cb;
    if (t + 1 < nt) {
      const int k1 = (t + 1) << 5;
      gload16(gA0 + k1, lA0 + nb);
      gload16(gA1 + k1, lA1 + nb);
      gload16(gB0 + k1, lB0 + nb);
      gload16(gB1 + k1, lB1 + nb);
    }
    bf16x8 avf[4], bvf[4];
#pragma unroll
    for (int i = 0; i < 4; ++i) {
      int ra = wm + i * 16 + rl;
      avf[i] = *(const bf16x8*)&As[cb + ra * 32 + ((kb ^ (ra & 3)) << 3)];
      int rb = wn + i * 16 + rl;
      bvf[i] = *(const bf16x8*)&Bs[cb + rb * 32 + ((kb ^ (rb & 3)) << 3)];
    }
#pragma unroll
    for (int i = 0; i < 4; ++i)
#pragma unroll
      for (int j = 0; j < 4; ++j)
        acc[i][j] = __builtin_amdgcn_mfma_f32_16x16x32_bf16(avf[i], bvf[j],
                                                            acc[i][j], 0, 0, 0);
    __syncthreads();
  }

#pragma unroll
  for (int i = 0; i < 4; ++i) {
#pragma unroll
    for (int rr = 0; rr < 4; ++rr) {
      int row = m0 + wm + i * 16 + kb * 4 + rr;
      float sm = stats[row * 2 + 0];
      float sq = stats[row * 2 + 1];
      float mu = sm * (1.f / 384.f);
      float rs = rsqrtf(sq * (1.f / 384.f) - mu * mu + 1e-6f);
#pragma unroll
      for (int j = 0; j < 4; ++j) {
        int col = wn + j * 16 + rl;
        float v = rs * (acc[i][j][rr] - mu * fcs[col]) + fcc[col];
        C[(size_t)row * Np + col] = __float2bfloat16(v);
      }
    }
  }
}

// ---------------------------------------------------------------------------
// Dual GEMM: region 1 (blocks 0..566): val = af @ Wvt + bv (bf16 out,
// Np=384, ntx=3). Region 2 (blocks 567..944): offatt = aq @ Wofat + bofat
// (f32 out, Np=256, ntx=2).
// ---------------------------------------------------------------------------
__global__ __launch_bounds__(256) void gemm_dual(
    const __hip_bfloat16* __restrict__ A1, const __hip_bfloat16* __restrict__ W1,
    const float* __restrict__ bias1, void* __restrict__ C1,
    const __hip_bfloat16* __restrict__ A2, const __hip_bfloat16* __restrict__ W2,
    const float* __restrict__ bias2, void* __restrict__ C2) {
  __shared__ __align__(16) ushort As[2 * 128 * 32];
  __shared__ __align__(16) ushort Bs[2 * 128 * 32];
  const int tid = threadIdx.x;
  const int gbid = blockIdx.x;
  const bool r2 = gbid >= 567;
  const __hip_bfloat16* A = r2 ? A2 : A1;
  const __hip_bfloat16* Wt = r2 ? W2 : W1;
  const float* bias = r2 ? bias2 : bias1;
  void* Cv = r2 ? C2 : C1;
  const int Np = r2 ? 256 : 384, ntx = r2 ? 2 : 3;
  const int lbid = r2 ? gbid - 567 : gbid;
  const int lnwg = r2 ? 378 : 567;
  const int K = 384;

  const int tile = xcd_chunk(lbid, lnwg);
  const int tx = tile % ntx, ty = tile / ntx;
  const int m0 = ty * 128, n0 = tx * 128;

  const int lane = tid & 63, wv = tid >> 6;
  const int wm = (wv >> 1) * 64, wn = (wv & 1) * 64;
  const int rl = lane & 15, kb = lane >> 4;

  const int c0 = wv * 64 + lane;
  const int c1 = c0 + 256;
  const int r0c = c0 >> 2, b0 = (c0 & 3) ^ (r0c & 3);
  const int r1c = c1 >> 2, b1 = (c1 & 3) ^ (r1c & 3);
  const ushort* gA0 = (const ushort*)A + (size_t)(m0 + r0c) * K + b0 * 8;
  const ushort* gA1 = (const ushort*)A + (size_t)(m0 + r1c) * K + b1 * 8;
  const ushort* gB0 = (const ushort*)Wt + (size_t)(n0 + r0c) * K + b0 * 8;
  const ushort* gB1 = (const ushort*)Wt + (size_t)(n0 + r1c) * K + b1 * 8;
  ushort* lA0 = &As[(size_t)wv * 512];
  ushort* lA1 = &As[(size_t)wv * 512 + 2048];
  ushort* lB0 = &Bs[(size_t)wv * 512];
  ushort* lB1 = &Bs[(size_t)wv * 512 + 2048];

  f32x4 acc[4][4] = {};
  const int nt = K >> 5;

  gload16(gA0, lA0);
  gload16(gA1, lA1);
  gload16(gB0, lB0);
  gload16(gB1, lB1);
  __syncthreads();

  for (int t = 0; t < nt; ++t) {
    const int cb = (t & 1) << 12;
    const int nb = 4096 - cb;
    if (t + 1 < nt) {
      const int k1 = (t + 1) << 5;
      gload16(gA0 + k1, lA0 + nb);
      gload16(gA1 + k1, lA1 + nb);
      gload16(gB0 + k1, lB0 + nb);
      gload16(gB1 + k1, lB1 + nb);
    }
    bf16x8 avf[4], bvf[4];
#pragma unroll
    for (int i = 0; i < 4; ++i) {
      int ra = wm + i * 16 + rl;
      avf[i] = *(const bf16x8*)&As[cb + ra * 32 + ((kb ^ (ra & 3)) << 3)];
      int rb = wn + i * 16 + rl;
      bvf[i] = *(const bf16x8*)&Bs[cb + rb * 32 + ((kb ^ (rb & 3)) << 3)];
    }
#pragma unroll
    for (int i = 0; i < 4; ++i)
#pragma unroll
      for (int j = 0; j < 4; ++j)
        acc[i][j] = __builtin_amdgcn_mfma_f32_16x16x32_bf16(avf[i], bvf[j],
                                                            acc[i][j], 0, 0, 0);
    __syncthreads();
  }

#pragma unroll
  for (int i = 0; i < 4; ++i) {
#pragma unroll
    for (int j = 0; j < 4; ++j) {
      int col = n0 + wn + j * 16 + rl;
      float bsv = bias[col];
#pragma unroll
      for (int rr = 0; rr < 4; ++rr) {
        int row = m0 + wm + i * 16 + kb * 4 + rr;
        size_t o = (size_t)row * Np + col;
        float v = acc[i][j][rr] + bsv;
        if (!r2) ((__hip_bfloat16*)Cv)[o] = __float2bfloat16(v);
        else ((float*)Cv)[o] = v;
      }
    }
  }
}

// ---------------------------------------------------------------------------
// Sampling phase 1 (dense): one THREAD per (t,h,l,p); emits 4 tap-corner
// records rec = (bf16(tap_weight) << 16) | (y*Wl + x). XCD-chunked.
// ---------------------------------------------------------------------------
__global__ __launch_bounds__(256) void msdeform_prep(
    const float* __restrict__ offatt, uint* __restrict__ taps) {
  int tile = xcd_chunk(blockIdx.x, gridDim.x);
  int id = tile * 256 + (int)threadIdx.x;
  if (id >= TOKS * 72) return;
  int t = id / 72, r = id - t * 72;
  int h = r / 12, lp = r - h * 12;
  int l = lp >> 2;
  int nq = t % NTOK;

  int pos, Hq, Wq;
  if (nq < 9216)       { pos = nq;         Hq = 96; Wq = 96; }
  else if (nq < 11520) { pos = nq - 9216;  Hq = 48; Wq = 48; }
  else                 { pos = nq - 11520; Hq = 24; Wq = 24; }
  int iq = pos / Wq, jq = pos - iq * Wq;
  float refx = (jq + 0.5f) / (float)Wq;
  float refy = (iq + 0.5f) / (float)Hq;

  const float* lg = offatt + (size_t)t * 256 + 144 + h * 12;
  float mx = -1e30f;
#pragma unroll
  for (int i = 0; i < 12; ++i) mx = fmaxf(mx, lg[i]);
  float sden = 0.f;
#pragma unroll
  for (int i = 0; i < 12; ++i) sden += __expf(lg[i] - mx);
  float aw = __expf(lg[lp] - mx) / sden;

  float ox = offatt[(size_t)t * 256 + h * 24 + lp * 2 + 0];
  float oy = offatt[(size_t)t * 256 + h * 24 + lp * 2 + 1];

  int Wl = 96 >> l;

  float xx = refx * (float)Wl + ox - 0.5f;
  float yy = refy * (float)Wl + oy - 0.5f;
  float x0f = floorf(xx), y0f = floorf(yy);
  int x0 = (int)x0f, y0 = (int)y0f;
  float wx = xx - x0f, wy = yy - y0f;

  bool vx0 = (x0 >= 0) & (x0 < Wl), vx1 = (x0 + 1 >= 0) & (x0 + 1 < Wl);
  bool vy0 = (y0 >= 0) & (y0 < Wl), vy1 = (y0 + 1 >= 0) & (y0 + 1 < Wl);
  int x0c = min(max(x0, 0), Wl - 1), x1c = min(max(x0 + 1, 0), Wl - 1);
  int y0c = min(max(y0, 0), Wl - 1), y1c = min(max(y0 + 1, 0), Wl - 1);

  float w00 = (vy0 && vx0) ? aw * (1.f - wx) * (1.f - wy) : 0.f;
  float w01 = (vy0 && vx1) ? aw * wx * (1.f - wy) : 0.f;
  float w10 = (vy1 && vx0) ? aw * (1.f - wx) * wy : 0.f;
  float w11 = (vy1 && vx1) ? aw * wx * wy : 0.f;

  uint4 rec;
  rec.x = ((uint)f2bf(w00) << 16) | (uint)(y0c * Wl + x0c);
  rec.y = ((uint)f2bf(w01) << 16) | (uint)(y0c * Wl + x1c);
  rec.z = ((uint)f2bf(w10) << 16) | (uint)(y1c * Wl + x0c);
  rec.w = ((uint)f2bf(w11) << 16) | (uint)(y1c * Wl + x1c);
  *(uint4*)&taps[((size_t)(t * NHEADS + h)) * 48 + lp * 4] = rec;
}

// ---------------------------------------------------------------------------
// Sampling phase 2: one wave per (t,h). 8-lane groups; iteration i loads
// 8 tap records (dword) and 8x128B of value via dwordx4. XCD-chunked.
// First 189 blocks also zero the LN stats buffer for the following Wout.
// ---------------------------------------------------------------------------
__global__ __launch_bounds__(256) void msdeform_gather(
    const __hip_bfloat16* __restrict__ value, const uint* __restrict__ taps,
    __hip_bfloat16* __restrict__ samp, float* __restrict__ stats) {
  if (blockIdx.x < 189) stats[blockIdx.x * 256 + threadIdx.x] = 0.f;

  int swz = xcd_chunk(blockIdx.x, gridDim.x);
  int wid = __builtin_amdgcn_readfirstlane(swz * 4 + ((int)threadIdx.x >> 6));
  int lane = threadIdx.x & 63;
  int g = lane >> 3, sub = lane & 7;
  int sub16 = sub * 16;

  int t = wid / NHEADS;
  int h = wid - t * NHEADS;
  int b = t / NTOK;

  const char* vb = (const char*)value + ((size_t)(b * NTOK) * DIMC + h * CHD) * 2;
  const char* vbl[3] = {vb, vb + 9216 * DIMC * 2, vb + 11520 * DIMC * 2};

  const uint* tp = taps + (size_t)wid * 48 + g;

  float acc[8] = {0.f, 0.f, 0.f, 0.f, 0.f, 0.f, 0.f, 0.f};
#pragma unroll
  for (int i = 0; i < 6; ++i) {
    uint rec = tp[i * 8];
    float wf = bf_hi(rec);
    uint off = (rec & 0x3fffu) * (uint)(DIMC * 2) + (uint)sub16;
    uint4 d = *(const uint4*)(vbl[i >> 1] + off);
    acc[0] = fmaf(wf, bf_lo(d.x), acc[0]);
    acc[1] = fmaf(wf, bf_hi(d.x), acc[1]);
    acc[2] = fmaf(wf, bf_lo(d.y), acc[2]);
    acc[3] = fmaf(wf, bf_hi(d.y), acc[3]);
    acc[4] = fmaf(wf, bf_lo(d.z), acc[4]);
    acc[5] = fmaf(wf, bf_hi(d.z), acc[5]);
    acc[6] = fmaf(wf, bf_lo(d.w), acc[6]);
    acc[7] = fmaf(wf, bf_hi(d.w), acc[7]);
  }

#pragma unroll
  for (int r = 0; r < 8; ++r) {
    acc[r] += __shfl_xor(acc[r], 8, 64);
    acc[r] += __shfl_xor(acc[r], 16, 64);
    acc[r] += __shfl_xor(acc[r], 32, 64);
  }

  if (lane < 8) {
    uint4 o;
    o.x = ((uint)f2bf(acc[1]) << 16) | f2bf(acc[0]);
    o.y = ((uint)f2bf(acc[3]) << 16) | f2bf(acc[2]);
    o.z = ((uint)f2bf(acc[5]) << 16) | f2bf(acc[4]);
    o.w = ((uint)f2bf(acc[7]) << 16) | f2bf(acc[6]);
    *(uint4*)((char*)samp + (size_t)wid * 128 + sub16) = o;
  }
}

// ---------------------------------------------------------------------------
// Depthwise 3x3 + bias + exact GELU, 4 channels/thread.
// x bf16 [T][128] (padded), y bf16 [T][96].
// ---------------------------------------------------------------------------
__global__ __launch_bounds__(256) void dwconv_gelu(
    const __hip_bfloat16* __restrict__ x, const float* __restrict__ w,
    const float* __restrict__ bias, __hip_bfloat16* __restrict__ y) {
  int id = blockIdx.x * blockDim.x + threadIdx.x;
  if (id >= TOKS * 24) return;
  int g = id % 24;
  int tn = id / 24;
  int ch0 = g * 4;
  int b = tn / NTOK, nq = tn - b * NTOK;

  int pos, Hl, Wl, st;
  if (nq < 9216)       { pos = nq;         Hl = 96; Wl = 96; st = 0; }
  else if (nq < 11520) { pos = nq - 9216;  Hl = 48; Wl = 48; st = 9216; }
  else                 { pos = nq - 11520; Hl = 24; Wl = 24; st = 11520; }
  int i = pos / Wl, j = pos - i * Wl;

  f32x4 acc = *(const f32x4*)&bias[ch0];
#pragma unroll
  for (int di = 0; di < 3; ++di) {
#pragma unroll
    for (int dj = 0; dj < 3; ++dj) {
      int ii = i + di - 1, jj = j + dj - 1;
      if (ii >= 0 && ii < Hl && jj >= 0 && jj < Wl) {
        uint2 d = *(const uint2*)&x[((size_t)(b * NTOK + st + ii * Wl + jj)) * 128 + ch0];
        f32x4 wv = *(const f32x4*)&w[(di * 3 + dj) * 96 + ch0];
        acc[0] = fmaf(bf_lo(d.x), wv[0], acc[0]);
        acc[1] = fmaf(bf_hi(d.x), wv[1], acc[1]);
        acc[2] = fmaf(bf_lo(d.y), wv[2], acc[2]);
        acc[3] = fmaf(bf_hi(d.y), wv[3], acc[3]);
      }
    }
  }
  uint2 o;
  float g0 = 0.5f * acc[0] * (1.f + erff(acc[0] * 0.70710678f));
  float g1 = 0.5f * acc[1] * (1.f + erff(acc[1] * 0.70710678f));
  float g2 = 0.5f * acc[2] * (1.f + erff(acc[2] * 0.70710678f));
  float g3 = 0.5f * acc[3] * (1.f + erff(acc[3] * 0.70710678f));
  o.x = ((uint)f2bf(g1) << 16) | f2bf(g0);
  o.y = ((uint)f2bf(g3) << 16) | f2bf(g2);
  *(uint2*)((char*)y + (size_t)tn * 192 + ch0 * 2) = o;
}

// ---------------------------------------------------------------------------
extern "C" void kernel_launch(void* const* d_in, const int* in_sizes, int n_in,
                              void* d_out, int out_size, void* d_ws, size_t ws_size,
                              hipStream_t stream) {
  const float* query = (const float*)d_in[0];
  const float* feat   = (const float*)d_in[2];
  const float* cti_qw = (const float*)d_in[7];
  const float* cti_qb = (const float*)d_in[8];
  const float* cti_fw = (const float*)d_in[9];
  const float* cti_fb = (const float*)d_in[10];
  const float* cf_qw  = (const float*)d_in[11];
  const float* cf_qb  = (const float*)d_in[12];
  const float* cf_fw  = (const float*)d_in[13];
  const float* cf_fb  = (const float*)d_in[14];
  const float* Wv     = (const float*)d_in[15];
  const float* bv     = (const float*)d_in[16];
  const float* Woff   = (const float*)d_in[17];
  const float* boff   = (const float*)d_in[18];
  const float* Watt   = (const float*)d_in[19];
  const float* batt   = (const float*)d_in[20];
  const float* Wo     = (const float*)d_in[21];
  const float* bo     = (const float*)d_in[22];
  const float* ffw    = (const float*)d_in[23];
  const float* ffb    = (const float*)d_in[24];
  const float* fc1w   = (const float*)d_in[25];
  const float* fc1b   = (const float*)d_in[26];
  const float* dww    = (const float*)d_in[27];
  const float* dwb    = (const float*)d_in[28];
  const float* fc2w   = (const float*)d_in[29];
  const float* fc2b   = (const float*)d_in[30];
  float* out = (float*)d_out;

  char* ws = (char*)d_ws;
  __hip_bfloat16* qn  = (__hip_bfloat16*)ws;                // T*384 bf16
  __hip_bfloat16* aq  = (__hip_bfloat16*)(ws + 37158912);   // T*384 bf16
  __hip_bfloat16* af  = (__hip_bfloat16*)(ws + 55738368);   // T*384 bf16
  __hip_bfloat16* val = (__hip_bfloat16*)(ws + 74317824);   // T*384 bf16
  float* offatt       = (float*)(ws + 92897280);            // T*256 f32
  char* wbase = ws + 117669888;
  __hip_bfloat16* Wvt   = (__hip_bfloat16*)(wbase + 0);
  __hip_bfloat16* Wot   = (__hip_bfloat16*)(wbase + 589824);
  __hip_bfloat16* Wofat = (__hip_bfloat16*)(wbase + 1179648);
  __hip_bfloat16* fc1t  = (__hip_bfloat16*)(wbase + 1376256);
  __hip_bfloat16* fc2t  = (__hip_bfloat16*)(wbase + 1474560);
  float* bofat          = (float*)(wbase + 1548288);
  float* fcs            = (float*)(wbase + 1549312);        // 128 f32
  float* fcc            = (float*)(wbase + 1549824);        // 128 f32
  // sampling tap table (tail region): T*6*48 uints = 27.87MB
  uint* taps = (uint*)(ws + 119220224);
  // reuse regions
  __hip_bfloat16* samp  = af;
  __hip_bfloat16* outbf = val;                              // dead after gather
  __hip_bfloat16* h1    = (__hip_bfloat16*)offatt;          // T*128 bf16
  __hip_bfloat16* h2    = (__hip_bfloat16*)(ws + 92897280 + 6193152); // T*96 bf16
  float* stats          = (float*)(ws + 92897280 + 6193152 + 4644864); // T*2 f32

  dim3 blk(256);

  // convert weights (+LN-fold vectors) + fused LN3
  prelude_kernel<<<576 + TOKS / 4, blk, 0, stream>>>(
      Wv, Woff, Watt, Wo, fc1w, fc2w, boff, batt, fc1b, ffw, ffb, Wvt, Wot,
      Wofat, fc1t, fc2t, bofat, fcs, fcc, query, feat, cti_qw, cti_qb, cti_fw,
      cti_fb, cf_qw, cf_qb, cf_fw, cf_fb, qn, aq, af);

  // val = af @ Wvt + bv (bf16)  ||  offatt = aq @ Wofat + bofat (f32)
  gemm_dual<<<945, blk, 0, stream>>>(af, Wvt, bv, val, aq, Wofat, bofat, offatt);

  // dense prep, then wide-load gather (+stats zero)
  msdeform_prep<<<(TOKS * 72) / 256, blk, 0, stream>>>(offatt, taps);
  msdeform_gather<<<(TOKS * NHEADS) / 4, blk, 0, stream>>>(val, taps, samp, stats);

  // out = samp @ Wout + bout + qn; also bf16 copy + LN stats
  gemm_wout<<<567, blk, 0, stream>>>(samp, Wot, bo, qn, out, outbf, stats);

  // h1 = LN(out) @ fc1 + fc1b, LN folded via stats/fcs/fcc
  gemm_fc1<<<189, blk, 0, stream>>>(outbf, fc1t, stats, fcs, fcc, h1);

  dwconv_gelu<<<(TOKS * 24 + 255) / 256, blk, 0, stream>>>(h1, dww, dwb, h2);
  // out += h2 @ fc2 + fc2_b  (K=96)
  gemm_mfma<2, 0><<<567, blk, 0, stream>>>(h2, fc2t, fc2b, nullptr, out, 96, 384, 3);
}

// Round 14
// 183.168 us; speedup vs baseline: 1.0791x; 1.0791x over previous
//
#include <hip/hip_runtime.h>
#include <hip/hip_bf16.h>
#include <hip/hip_fp16.h>
#include <cstdint>
#include <cstddef>

#define NB 2
#define NTOK 12096
#define TOKS (NB * NTOK)   // 24192
#define DIMC 384
#define NHEADS 6
#define CHD 64

typedef __attribute__((ext_vector_type(8))) __bf16 bf16x8;
typedef __attribute__((ext_vector_type(4))) float f32x4;

__device__ __forceinline__ float wave_reduce_add(float v) {
#pragma unroll
  for (int o = 32; o > 0; o >>= 1) v += __shfl_xor(v, o, 64);
  return v;
}

__device__ __forceinline__ float bf_lo(uint u) {
  union { uint i; float f; } c; c.i = u << 16; return c.f;
}
__device__ __forceinline__ float bf_hi(uint u) {
  union { uint i; float f; } c; c.i = u & 0xffff0000u; return c.f;
}
__device__ __forceinline__ ushort f2bf(float x) {
  union { __hip_bfloat16 b; ushort u; } c; c.b = __float2bfloat16(x); return c.u;
}
__device__ __forceinline__ uint pk2bf(float a, float b) {
  return ((uint)f2bf(b) << 16) | f2bf(a);
}

// bijective XCD-chunked id mapping: 8 contiguous chunks, chunk i on XCD i
__device__ __forceinline__ int xcd_chunk(int bid, int nwg) {
  int xcd = bid & 7, off = bid >> 3;
  int q = nwg >> 3, r = nwg & 7;
  return (xcd < r ? xcd * (q + 1) : r * (q + 1) + (xcd - r) * q) + off;
}

// async global->LDS, 16B per lane; LDS dest is wave-uniform base + lane*16
__device__ __forceinline__ void gload16(const ushort* g, ushort* l) {
  __builtin_amdgcn_global_load_lds(
      (const __attribute__((address_space(1))) uint*)g,
      (__attribute__((address_space(3))) uint*)l, 16, 0, 0);
}

// ---------------------------------------------------------------------------
// Prelude: blocks 0..575 convert weights (fp32 [K][N] -> bf16 [Np][K] + padded
// biases); blocks 576.. run the fused LN3 (q build + qn/aq/af).
// ---------------------------------------------------------------------------
__global__ __launch_bounds__(256) void prelude_kernel(
    const float* __restrict__ Wv, const float* __restrict__ Woff,
    const float* __restrict__ Watt, const float* __restrict__ Wo,
    const float* __restrict__ fc1, const float* __restrict__ fc2,
    const float* __restrict__ boff, const float* __restrict__ batt,
    const float* __restrict__ fc1b,
    __hip_bfloat16* __restrict__ Wvt, __hip_bfloat16* __restrict__ Wot,
    __hip_bfloat16* __restrict__ Wofat, __hip_bfloat16* __restrict__ fc1t,
    __hip_bfloat16* __restrict__ fc2t, float* __restrict__ bofat,
    float* __restrict__ fc1bp,
    const float* __restrict__ query, const float* __restrict__ feat,
    const float* __restrict__ w1, const float* __restrict__ b1,
    const float* __restrict__ w2, const float* __restrict__ b2,
    const float* __restrict__ w3, const float* __restrict__ b3,
    const float* __restrict__ w4, const float* __restrict__ b4,
    __hip_bfloat16* __restrict__ qn, __hip_bfloat16* __restrict__ aq,
    __hip_bfloat16* __restrict__ af) {
  if (blockIdx.x < 576) {
    int id = blockIdx.x * 256 + threadIdx.x;
    int k = id % 384, n = id / 384;
    Wvt[(size_t)n * 384 + k] = __float2bfloat16(Wv[(size_t)k * 384 + n]);
    Wot[(size_t)n * 384 + k] = __float2bfloat16(Wo[(size_t)k * 384 + n]);
    if (n < 256) {
      float v = 0.f;
      if (n < 144) v = Woff[(size_t)k * 144 + n];
      else if (n < 216) v = Watt[(size_t)k * 72 + (n - 144)];
      Wofat[(size_t)n * 384 + k] = __float2bfloat16(v);
    }
    if (n < 128)
      fc1t[(size_t)n * 384 + k] = __float2bfloat16(n < 96 ? fc1[(size_t)k * 96 + n] : 0.f);
    if (k < 96)
      fc2t[(size_t)n * 96 + k] = __float2bfloat16(fc2[(size_t)k * 384 + n]);
    if (id < 256) bofat[id] = id < 144 ? boff[id] : (id < 216 ? batt[id - 144] : 0.f);
    if (id < 128) fc1bp[id] = id < 96 ? fc1b[id] : 0.f;
    return;
  }

  int wid = ((blockIdx.x - 576) * blockDim.x + threadIdx.x) >> 6;
  if (wid >= TOKS) return;
  int lane = threadIdx.x & 63;
  int bb = wid / NTOK;
  int nq = wid - bb * NTOK;

  float x[6];
  const float* qp = query + (size_t)wid * DIMC + lane;
#pragma unroll
  for (int i = 0; i < 6; ++i) x[i] = qp[64 * i];
  if (nq >= 9216 && nq < 11520) {
    const float* fp = feat + ((size_t)bb * 2304 + (nq - 9216)) * DIMC + lane;
#pragma unroll
    for (int i = 0; i < 6; ++i) x[i] += fp[64 * i];
  }

  float s = 0.f, ss = 0.f;
#pragma unroll
  for (int i = 0; i < 6; ++i) { s += x[i]; ss += x[i] * x[i]; }
  s = wave_reduce_add(s); ss = wave_reduce_add(ss);
  float mean = s * (1.f / DIMC);
  float rs = rsqrtf(ss * (1.f / DIMC) - mean * mean + 1e-6f);

  float qv[6], fv[6];
  __hip_bfloat16* qnp = qn + (size_t)wid * DIMC + lane;
#pragma unroll
  for (int i = 0; i < 6; ++i) {
    int e = lane + 64 * i;
    float xh = (x[i] - mean) * rs;
    qv[i] = xh * w1[e] + b1[e];
    fv[i] = xh * w2[e] + b2[e];
    qnp[64 * i] = __float2bfloat16(qv[i]);
  }

  s = 0.f; ss = 0.f;
#pragma unroll
  for (int i = 0; i < 6; ++i) { s += qv[i]; ss += qv[i] * qv[i]; }
  s = wave_reduce_add(s); ss = wave_reduce_add(ss);
  float m2 = s * (1.f / DIMC);
  float rs2 = rsqrtf(ss * (1.f / DIMC) - m2 * m2 + 1e-6f);
  __hip_bfloat16* aqp = aq + (size_t)wid * DIMC + lane;
#pragma unroll
  for (int i = 0; i < 6; ++i) {
    int e = lane + 64 * i;
    aqp[64 * i] = __float2bfloat16((qv[i] - m2) * rs2 * w3[e] + b3[e]);
  }

  s = 0.f; ss = 0.f;
#pragma unroll
  for (int i = 0; i < 6; ++i) { s += fv[i]; ss += fv[i] * fv[i]; }
  s = wave_reduce_add(s); ss = wave_reduce_add(ss);
  float m3 = s * (1.f / DIMC);
  float rs3 = rsqrtf(ss * (1.f / DIMC) - m3 * m3 + 1e-6f);
  __hip_bfloat16* afp = af + (size_t)wid * DIMC + lane;
#pragma unroll
  for (int i = 0; i < 6; ++i) {
    int e = lane + 64 * i;
    afp[64 * i] = __float2bfloat16((fv[i] - m3) * rs3 * w4[e] + b4[e]);
  }
}

// ---------------------------------------------------------------------------
// ffn_norm: fp32 in -> bf16 out. Vectorized: lane covers cols {lane*2,
// lane*2+1} + {0,128,256} via 3x dwordx2 loads + 3x packed-bf16 dword stores.
// ---------------------------------------------------------------------------
__global__ __launch_bounds__(256) void ln_kernel(
    const float* __restrict__ x, const float* __restrict__ w,
    const float* __restrict__ b, __hip_bfloat16* __restrict__ y) {
  int wid = (blockIdx.x * blockDim.x + threadIdx.x) >> 6;
  if (wid >= TOKS) return;
  int lane = threadIdx.x & 63;
  int c0 = lane * 2;

  float2 v[3];
  const float* xp = x + (size_t)wid * DIMC;
#pragma unroll
  for (int i = 0; i < 3; ++i) v[i] = *(const float2*)&xp[c0 + 128 * i];

  float s = 0.f, ss = 0.f;
#pragma unroll
  for (int i = 0; i < 3; ++i) {
    s += v[i].x + v[i].y;
    ss += v[i].x * v[i].x + v[i].y * v[i].y;
  }
  s = wave_reduce_add(s); ss = wave_reduce_add(ss);
  float mean = s * (1.f / DIMC);
  float rs = rsqrtf(ss * (1.f / DIMC) - mean * mean + 1e-6f);

  uint* yp = (uint*)((char*)y + (size_t)wid * DIMC * 2);
#pragma unroll
  for (int i = 0; i < 3; ++i) {
    int e = c0 + 128 * i;
    float2 wv = *(const float2*)&w[e];
    float2 bv = *(const float2*)&b[e];
    float a = (v[i].x - mean) * rs * wv.x + bv.x;
    float c = (v[i].y - mean) * rs * wv.y + bv.y;
    yp[lane + 64 * i] = pk2bf(a, c);
  }
}

// ---------------------------------------------------------------------------
// bf16 MFMA GEMM: 128x128 tile, 4 waves, 2-phase double-buffered
// global_load_lds pipeline, pre-swizzled source, bijective XCD-chunked
// tile mapping.
// ---------------------------------------------------------------------------
template <int EPI, int OUTBF16>
__global__ __launch_bounds__(256) void gemm_mfma(
    const __hip_bfloat16* __restrict__ A, const __hip_bfloat16* __restrict__ Wt,
    const float* __restrict__ bias, const void* __restrict__ Rv,
    void* __restrict__ Cv, int K, int Np, int ntx) {
  __shared__ __align__(16) ushort As[2 * 128 * 32];
  __shared__ __align__(16) ushort Bs[2 * 128 * 32];
  const int tid = threadIdx.x;
  const int tile = xcd_chunk(blockIdx.x, gridDim.x);
  const int tx = tile % ntx, ty = tile / ntx;
  const int m0 = ty * 128, n0 = tx * 128;

  const int lane = tid & 63, wv = tid >> 6;
  const int wm = (wv >> 1) * 64, wn = (wv & 1) * 64;
  const int rl = lane & 15, kb = lane >> 4;

  const int c0 = wv * 64 + lane;
  const int c1 = c0 + 256;
  const int r0c = c0 >> 2, b0 = (c0 & 3) ^ (r0c & 3);
  const int r1c = c1 >> 2, b1 = (c1 & 3) ^ (r1c & 3);
  const ushort* gA0 = (const ushort*)A + (size_t)(m0 + r0c) * K + b0 * 8;
  const ushort* gA1 = (const ushort*)A + (size_t)(m0 + r1c) * K + b1 * 8;
  const ushort* gB0 = (const ushort*)Wt + (size_t)(n0 + r0c) * K + b0 * 8;
  const ushort* gB1 = (const ushort*)Wt + (size_t)(n0 + r1c) * K + b1 * 8;
  ushort* lA0 = &As[(size_t)wv * 512];
  ushort* lA1 = &As[(size_t)wv * 512 + 2048];
  ushort* lB0 = &Bs[(size_t)wv * 512];
  ushort* lB1 = &Bs[(size_t)wv * 512 + 2048];

  f32x4 acc[4][4] = {};
  const int nt = K >> 5;

  gload16(gA0, lA0);
  gload16(gA1, lA1);
  gload16(gB0, lB0);
  gload16(gB1, lB1);
  __syncthreads();

  for (int t = 0; t < nt; ++t) {
    const int cb = (t & 1) << 12;
    const int nb = 4096 - cb;
    if (t + 1 < nt) {
      const int k1 = (t + 1) << 5;
      gload16(gA0 + k1, lA0 + nb);
      gload16(gA1 + k1, lA1 + nb);
      gload16(gB0 + k1, lB0 + nb);
      gload16(gB1 + k1, lB1 + nb);
    }
    bf16x8 avf[4], bvf[4];
#pragma unroll
    for (int i = 0; i < 4; ++i) {
      int ra = wm + i * 16 + rl;
      avf[i] = *(const bf16x8*)&As[cb + ra * 32 + ((kb ^ (ra & 3)) << 3)];
      int rb = wn + i * 16 + rl;
      bvf[i] = *(const bf16x8*)&Bs[cb + rb * 32 + ((kb ^ (rb & 3)) << 3)];
    }
#pragma unroll
    for (int i = 0; i < 4; ++i)
#pragma unroll
      for (int j = 0; j < 4; ++j)
        acc[i][j] = __builtin_amdgcn_mfma_f32_16x16x32_bf16(avf[i], bvf[j],
                                                            acc[i][j], 0, 0, 0);
    __syncthreads();
  }

#pragma unroll
  for (int i = 0; i < 4; ++i) {
#pragma unroll
    for (int j = 0; j < 4; ++j) {
      int col = n0 + wn + j * 16 + rl;
      float bsv = bias[col];
#pragma unroll
      for (int rr = 0; rr < 4; ++rr) {
        int row = m0 + wm + i * 16 + kb * 4 + rr;
        size_t o = (size_t)row * Np + col;
        float v = acc[i][j][rr] + bsv;
        if (EPI == 1) v += __bfloat162float(((const __hip_bfloat16*)Rv)[o]);
        if (EPI == 2) v += ((const float*)Cv)[o];
        if (OUTBF16) ((__hip_bfloat16*)Cv)[o] = __float2bfloat16(v);
        else ((float*)Cv)[o] = v;
      }
    }
  }
}

// ---------------------------------------------------------------------------
// Dual GEMM: region 1 (blocks 0..566): val = af @ Wvt + bv (bf16 out,
// Np=384, ntx=3). Region 2 (blocks 567..944): offatt = aq @ Wofat + bofat
// (f32 out, Np=256, ntx=2).
// ---------------------------------------------------------------------------
__global__ __launch_bounds__(256) void gemm_dual(
    const __hip_bfloat16* __restrict__ A1, const __hip_bfloat16* __restrict__ W1,
    const float* __restrict__ bias1, void* __restrict__ C1,
    const __hip_bfloat16* __restrict__ A2, const __hip_bfloat16* __restrict__ W2,
    const float* __restrict__ bias2, void* __restrict__ C2) {
  __shared__ __align__(16) ushort As[2 * 128 * 32];
  __shared__ __align__(16) ushort Bs[2 * 128 * 32];
  const int tid = threadIdx.x;
  const int gbid = blockIdx.x;
  const bool r2 = gbid >= 567;
  const __hip_bfloat16* A = r2 ? A2 : A1;
  const __hip_bfloat16* Wt = r2 ? W2 : W1;
  const float* bias = r2 ? bias2 : bias1;
  void* Cv = r2 ? C2 : C1;
  const int Np = r2 ? 256 : 384, ntx = r2 ? 2 : 3;
  const int lbid = r2 ? gbid - 567 : gbid;
  const int lnwg = r2 ? 378 : 567;
  const int K = 384;

  const int tile = xcd_chunk(lbid, lnwg);
  const int tx = tile % ntx, ty = tile / ntx;
  const int m0 = ty * 128, n0 = tx * 128;

  const int lane = tid & 63, wv = tid >> 6;
  const int wm = (wv >> 1) * 64, wn = (wv & 1) * 64;
  const int rl = lane & 15, kb = lane >> 4;

  const int c0 = wv * 64 + lane;
  const int c1 = c0 + 256;
  const int r0c = c0 >> 2, b0 = (c0 & 3) ^ (r0c & 3);
  const int r1c = c1 >> 2, b1 = (c1 & 3) ^ (r1c & 3);
  const ushort* gA0 = (const ushort*)A + (size_t)(m0 + r0c) * K + b0 * 8;
  const ushort* gA1 = (const ushort*)A + (size_t)(m0 + r1c) * K + b1 * 8;
  const ushort* gB0 = (const ushort*)Wt + (size_t)(n0 + r0c) * K + b0 * 8;
  const ushort* gB1 = (const ushort*)Wt + (size_t)(n0 + r1c) * K + b1 * 8;
  ushort* lA0 = &As[(size_t)wv * 512];
  ushort* lA1 = &As[(size_t)wv * 512 + 2048];
  ushort* lB0 = &Bs[(size_t)wv * 512];
  ushort* lB1 = &Bs[(size_t)wv * 512 + 2048];

  f32x4 acc[4][4] = {};
  const int nt = K >> 5;

  gload16(gA0, lA0);
  gload16(gA1, lA1);
  gload16(gB0, lB0);
  gload16(gB1, lB1);
  __syncthreads();

  for (int t = 0; t < nt; ++t) {
    const int cb = (t & 1) << 12;
    const int nb = 4096 - cb;
    if (t + 1 < nt) {
      const int k1 = (t + 1) << 5;
      gload16(gA0 + k1, lA0 + nb);
      gload16(gA1 + k1, lA1 + nb);
      gload16(gB0 + k1, lB0 + nb);
      gload16(gB1 + k1, lB1 + nb);
    }
    bf16x8 avf[4], bvf[4];
#pragma unroll
    for (int i = 0; i < 4; ++i) {
      int ra = wm + i * 16 + rl;
      avf[i] = *(const bf16x8*)&As[cb + ra * 32 + ((kb ^ (ra & 3)) << 3)];
      int rb = wn + i * 16 + rl;
      bvf[i] = *(const bf16x8*)&Bs[cb + rb * 32 + ((kb ^ (rb & 3)) << 3)];
    }
#pragma unroll
    for (int i = 0; i < 4; ++i)
#pragma unroll
      for (int j = 0; j < 4; ++j)
        acc[i][j] = __builtin_amdgcn_mfma_f32_16x16x32_bf16(avf[i], bvf[j],
                                                            acc[i][j], 0, 0, 0);
    __syncthreads();
  }

#pragma unroll
  for (int i = 0; i < 4; ++i) {
#pragma unroll
    for (int j = 0; j < 4; ++j) {
      int col = n0 + wn + j * 16 + rl;
      float bsv = bias[col];
#pragma unroll
      for (int rr = 0; rr < 4; ++rr) {
        int row = m0 + wm + i * 16 + kb * 4 + rr;
        size_t o = (size_t)row * Np + col;
        float v = acc[i][j][rr] + bsv;
        if (!r2) ((__hip_bfloat16*)Cv)[o] = __float2bfloat16(v);
        else ((float*)Cv)[o] = v;
      }
    }
  }
}

// ---------------------------------------------------------------------------
// Sampling phase 1 (dense): one THREAD per (t,h,l,p); emits 4 tap-corner
// records rec = (bf16(tap_weight) << 16) | (y*Wl + x). XCD-chunked.
// ---------------------------------------------------------------------------
__global__ __launch_bounds__(256) void msdeform_prep(
    const float* __restrict__ offatt, uint* __restrict__ taps) {
  int tile = xcd_chunk(blockIdx.x, gridDim.x);
  int id = tile * 256 + (int)threadIdx.x;
  if (id >= TOKS * 72) return;
  int t = id / 72, r = id - t * 72;
  int h = r / 12, lp = r - h * 12;
  int l = lp >> 2;
  int nq = t % NTOK;

  int pos, Hq, Wq;
  if (nq < 9216)       { pos = nq;         Hq = 96; Wq = 96; }
  else if (nq < 11520) { pos = nq - 9216;  Hq = 48; Wq = 48; }
  else                 { pos = nq - 11520; Hq = 24; Wq = 24; }
  int iq = pos / Wq, jq = pos - iq * Wq;
  float refx = (jq + 0.5f) / (float)Wq;
  float refy = (iq + 0.5f) / (float)Hq;

  const float* lg = offatt + (size_t)t * 256 + 144 + h * 12;
  float mx = -1e30f;
#pragma unroll
  for (int i = 0; i < 12; ++i) mx = fmaxf(mx, lg[i]);
  float sden = 0.f;
#pragma unroll
  for (int i = 0; i < 12; ++i) sden += __expf(lg[i] - mx);
  float aw = __expf(lg[lp] - mx) / sden;

  float ox = offatt[(size_t)t * 256 + h * 24 + lp * 2 + 0];
  float oy = offatt[(size_t)t * 256 + h * 24 + lp * 2 + 1];

  int Wl = 96 >> l;

  float xx = refx * (float)Wl + ox - 0.5f;
  float yy = refy * (float)Wl + oy - 0.5f;
  float x0f = floorf(xx), y0f = floorf(yy);
  int x0 = (int)x0f, y0 = (int)y0f;
  float wx = xx - x0f, wy = yy - y0f;

  bool vx0 = (x0 >= 0) & (x0 < Wl), vx1 = (x0 + 1 >= 0) & (x0 + 1 < Wl);
  bool vy0 = (y0 >= 0) & (y0 < Wl), vy1 = (y0 + 1 >= 0) & (y0 + 1 < Wl);
  int x0c = min(max(x0, 0), Wl - 1), x1c = min(max(x0 + 1, 0), Wl - 1);
  int y0c = min(max(y0, 0), Wl - 1), y1c = min(max(y0 + 1, 0), Wl - 1);

  float w00 = (vy0 && vx0) ? aw * (1.f - wx) * (1.f - wy) : 0.f;
  float w01 = (vy0 && vx1) ? aw * wx * (1.f - wy) : 0.f;
  float w10 = (vy1 && vx0) ? aw * (1.f - wx) * wy : 0.f;
  float w11 = (vy1 && vx1) ? aw * wx * wy : 0.f;

  uint4 rec;
  rec.x = ((uint)f2bf(w00) << 16) | (uint)(y0c * Wl + x0c);
  rec.y = ((uint)f2bf(w01) << 16) | (uint)(y0c * Wl + x1c);
  rec.z = ((uint)f2bf(w10) << 16) | (uint)(y1c * Wl + x0c);
  rec.w = ((uint)f2bf(w11) << 16) | (uint)(y1c * Wl + x1c);
  *(uint4*)&taps[((size_t)(t * NHEADS + h)) * 48 + lp * 4] = rec;
}

// ---------------------------------------------------------------------------
// Sampling phase 2: one wave per (t,h). 8-lane groups; iteration i loads
// 8 tap records (dword) and 8x128B of value via dwordx4. XCD-chunked.
// ---------------------------------------------------------------------------
__global__ __launch_bounds__(256) void msdeform_gather(
    const __hip_bfloat16* __restrict__ value, const uint* __restrict__ taps,
    __hip_bfloat16* __restrict__ samp) {
  int swz = xcd_chunk(blockIdx.x, gridDim.x);
  int wid = __builtin_amdgcn_readfirstlane(swz * 4 + ((int)threadIdx.x >> 6));
  int lane = threadIdx.x & 63;
  int g = lane >> 3, sub = lane & 7;
  int sub16 = sub * 16;

  int t = wid / NHEADS;
  int h = wid - t * NHEADS;
  int b = t / NTOK;

  const char* vb = (const char*)value + ((size_t)(b * NTOK) * DIMC + h * CHD) * 2;
  const char* vbl[3] = {vb, vb + 9216 * DIMC * 2, vb + 11520 * DIMC * 2};

  const uint* tp = taps + (size_t)wid * 48 + g;

  float acc[8] = {0.f, 0.f, 0.f, 0.f, 0.f, 0.f, 0.f, 0.f};
#pragma unroll
  for (int i = 0; i < 6; ++i) {
    uint rec = tp[i * 8];
    float wf = bf_hi(rec);
    uint off = (rec & 0x3fffu) * (uint)(DIMC * 2) + (uint)sub16;
    uint4 d = *(const uint4*)(vbl[i >> 1] + off);
    acc[0] = fmaf(wf, bf_lo(d.x), acc[0]);
    acc[1] = fmaf(wf, bf_hi(d.x), acc[1]);
    acc[2] = fmaf(wf, bf_lo(d.y), acc[2]);
    acc[3] = fmaf(wf, bf_hi(d.y), acc[3]);
    acc[4] = fmaf(wf, bf_lo(d.z), acc[4]);
    acc[5] = fmaf(wf, bf_hi(d.z), acc[5]);
    acc[6] = fmaf(wf, bf_lo(d.w), acc[6]);
    acc[7] = fmaf(wf, bf_hi(d.w), acc[7]);
  }

#pragma unroll
  for (int r = 0; r < 8; ++r) {
    acc[r] += __shfl_xor(acc[r], 8, 64);
    acc[r] += __shfl_xor(acc[r], 16, 64);
    acc[r] += __shfl_xor(acc[r], 32, 64);
  }

  if (lane < 8) {
    uint4 o;
    o.x = pk2bf(acc[0], acc[1]);
    o.y = pk2bf(acc[2], acc[3]);
    o.z = pk2bf(acc[4], acc[5]);
    o.w = pk2bf(acc[6], acc[7]);
    *(uint4*)((char*)samp + (size_t)wid * 128 + sub16) = o;
  }
}

// ---------------------------------------------------------------------------
// Depthwise 3x3 + bias + exact GELU, 8 channels/thread (uint4 taps).
// x bf16 [T][128] (padded), y bf16 [T][96].
// ---------------------------------------------------------------------------
__global__ __launch_bounds__(256) void dwconv_gelu(
    const __hip_bfloat16* __restrict__ x, const float* __restrict__ w,
    const float* __restrict__ bias, __hip_bfloat16* __restrict__ y) {
  int id = blockIdx.x * blockDim.x + threadIdx.x;
  if (id >= TOKS * 12) return;
  int g = id % 12;
  int tn = id / 12;
  int ch0 = g * 8;
  int b = tn / NTOK, nq = tn - b * NTOK;

  int pos, Hl, Wl, st;
  if (nq < 9216)       { pos = nq;         Hl = 96; Wl = 96; st = 0; }
  else if (nq < 11520) { pos = nq - 9216;  Hl = 48; Wl = 48; st = 9216; }
  else                 { pos = nq - 11520; Hl = 24; Wl = 24; st = 11520; }
  int i = pos / Wl, j = pos - i * Wl;

  float acc[8];
#pragma unroll
  for (int c = 0; c < 8; ++c) acc[c] = bias[ch0 + c];
#pragma unroll
  for (int di = 0; di < 3; ++di) {
#pragma unroll
    for (int dj = 0; dj < 3; ++dj) {
      int ii = i + di - 1, jj = j + dj - 1;
      if (ii >= 0 && ii < Hl && jj >= 0 && jj < Wl) {
        uint4 d = *(const uint4*)&x[((size_t)(b * NTOK + st + ii * Wl + jj)) * 128 + ch0];
        const float* wr = &w[(di * 3 + dj) * 96 + ch0];
        f32x4 w0 = *(const f32x4*)&wr[0];
        f32x4 w1 = *(const f32x4*)&wr[4];
        acc[0] = fmaf(bf_lo(d.x), w0[0], acc[0]);
        acc[1] = fmaf(bf_hi(d.x), w0[1], acc[1]);
        acc[2] = fmaf(bf_lo(d.y), w0[2], acc[2]);
        acc[3] = fmaf(bf_hi(d.y), w0[3], acc[3]);
        acc[4] = fmaf(bf_lo(d.z), w1[0], acc[4]);
        acc[5] = fmaf(bf_hi(d.z), w1[1], acc[5]);
        acc[6] = fmaf(bf_lo(d.w), w1[2], acc[6]);
        acc[7] = fmaf(bf_hi(d.w), w1[3], acc[7]);
      }
    }
  }
  float gl[8];
#pragma unroll
  for (int c = 0; c < 8; ++c)
    gl[c] = 0.5f * acc[c] * (1.f + erff(acc[c] * 0.70710678f));
  uint4 o;
  o.x = pk2bf(gl[0], gl[1]);
  o.y = pk2bf(gl[2], gl[3]);
  o.z = pk2bf(gl[4], gl[5]);
  o.w = pk2bf(gl[6], gl[7]);
  *(uint4*)((char*)y + (size_t)tn * 192 + ch0 * 2) = o;
}

// ---------------------------------------------------------------------------
extern "C" void kernel_launch(void* const* d_in, const int* in_sizes, int n_in,
                              void* d_out, int out_size, void* d_ws, size_t ws_size,
                              hipStream_t stream) {
  const float* query = (const float*)d_in[0];
  const float* feat   = (const float*)d_in[2];
  const float* cti_qw = (const float*)d_in[7];
  const float* cti_qb = (const float*)d_in[8];
  const float* cti_fw = (const float*)d_in[9];
  const float* cti_fb = (const float*)d_in[10];
  const float* cf_qw  = (const float*)d_in[11];
  const float* cf_qb  = (const float*)d_in[12];
  const float* cf_fw  = (const float*)d_in[13];
  const float* cf_fb  = (const float*)d_in[14];
  const float* Wv     = (const float*)d_in[15];
  const float* bv     = (const float*)d_in[16];
  const float* Woff   = (const float*)d_in[17];
  const float* boff   = (const float*)d_in[18];
  const float* Watt   = (const float*)d_in[19];
  const float* batt   = (const float*)d_in[20];
  const float* Wo     = (const float*)d_in[21];
  const float* bo     = (const float*)d_in[22];
  const float* ffw    = (const float*)d_in[23];
  const float* ffb    = (const float*)d_in[24];
  const float* fc1w   = (const float*)d_in[25];
  const float* fc1b   = (const float*)d_in[26];
  const float* dww    = (const float*)d_in[27];
  const float* dwb    = (const float*)d_in[28];
  const float* fc2w   = (const float*)d_in[29];
  const float* fc2b   = (const float*)d_in[30];
  float* out = (float*)d_out;

  char* ws = (char*)d_ws;
  __hip_bfloat16* qn  = (__hip_bfloat16*)ws;                // T*384 bf16
  __hip_bfloat16* aq  = (__hip_bfloat16*)(ws + 37158912);   // T*384 bf16
  __hip_bfloat16* af  = (__hip_bfloat16*)(ws + 55738368);   // T*384 bf16
  __hip_bfloat16* val = (__hip_bfloat16*)(ws + 74317824);   // T*384 bf16
  float* offatt       = (float*)(ws + 92897280);            // T*256 f32
  char* wbase = ws + 117669888;
  __hip_bfloat16* Wvt   = (__hip_bfloat16*)(wbase + 0);
  __hip_bfloat16* Wot   = (__hip_bfloat16*)(wbase + 589824);
  __hip_bfloat16* Wofat = (__hip_bfloat16*)(wbase + 1179648);
  __hip_bfloat16* fc1t  = (__hip_bfloat16*)(wbase + 1376256);
  __hip_bfloat16* fc2t  = (__hip_bfloat16*)(wbase + 1474560);
  float* bofat          = (float*)(wbase + 1548288);
  float* fc1bp          = (float*)(wbase + 1549312);
  // sampling tap table (tail region): T*6*48 uints = 27.87MB
  uint* taps = (uint*)(ws + 119220224);
  // reuse regions
  __hip_bfloat16* samp = af;
  __hip_bfloat16* lnf  = aq;
  __hip_bfloat16* h1   = (__hip_bfloat16*)offatt;           // T*128 bf16
  __hip_bfloat16* h2   = (__hip_bfloat16*)(ws + 92897280 + 6193152); // T*96 bf16

  dim3 blk(256);

  // convert weights (blocks 0..575) + fused LN3 (blocks 576..)
  prelude_kernel<<<576 + TOKS / 4, blk, 0, stream>>>(
      Wv, Woff, Watt, Wo, fc1w, fc2w, boff, batt, fc1b, Wvt, Wot, Wofat, fc1t,
      fc2t, bofat, fc1bp, query, feat, cti_qw, cti_qb, cti_fw, cti_fb, cf_qw,
      cf_qb, cf_fw, cf_fb, qn, aq, af);

  // val = af @ Wvt + bv (bf16)  ||  offatt = aq @ Wofat + bofat (f32)
  gemm_dual<<<945, blk, 0, stream>>>(af, Wvt, bv, val, aq, Wofat, bofat, offatt);

  // dense prep, then wide-load gather
  msdeform_prep<<<(TOKS * 72) / 256, blk, 0, stream>>>(offatt, taps);
  msdeform_gather<<<(TOKS * NHEADS) / 4, blk, 0, stream>>>(val, taps, samp);

  // out = samp @ Wout + bout + qn(bf16)  (f32 out)
  gemm_mfma<1, 0><<<567, blk, 0, stream>>>(samp, Wot, bo, qn, out, 384, 384, 3);

  ln_kernel<<<TOKS / 4, blk, 0, stream>>>(out, ffw, ffb, lnf);
  // h1 = lnf @ fc1 -> bf16 [T][128]
  gemm_mfma<0, 1><<<189, blk, 0, stream>>>(lnf, fc1t, fc1bp, nullptr, h1, 384, 128, 1);
  dwconv_gelu<<<(TOKS * 12 + 255) / 256, blk, 0, stream>>>(h1, dww, dwb, h2);
  // out += h2 @ fc2 + fc2_b  (K=96)
  gemm_mfma<2, 0><<<567, blk, 0, stream>>>(h2, fc2t, fc2b, nullptr, out, 96, 384, 3);
}

// Round 15
// 180.597 us; speedup vs baseline: 1.0945x; 1.0142x over previous
//
#include <hip/hip_runtime.h>
#include <hip/hip_bf16.h>
#include <hip/hip_fp16.h>
#include <cstdint>
#include <cstddef>

#define NB 2
#define NTOK 12096
#define TOKS (NB * NTOK)   // 24192
#define DIMC 384
#define NHEADS 6
#define CHD 64

typedef __attribute__((ext_vector_type(8))) __bf16 bf16x8;
typedef __attribute__((ext_vector_type(4))) float f32x4;

__device__ __forceinline__ float wave_reduce_add(float v) {
#pragma unroll
  for (int o = 32; o > 0; o >>= 1) v += __shfl_xor(v, o, 64);
  return v;
}

__device__ __forceinline__ float bf_lo(uint u) {
  union { uint i; float f; } c; c.i = u << 16; return c.f;
}
__device__ __forceinline__ float bf_hi(uint u) {
  union { uint i; float f; } c; c.i = u & 0xffff0000u; return c.f;
}
__device__ __forceinline__ ushort f2bf(float x) {
  union { __hip_bfloat16 b; ushort u; } c; c.b = __float2bfloat16(x); return c.u;
}
__device__ __forceinline__ uint pk2bf(float a, float b) {
  return ((uint)f2bf(b) << 16) | f2bf(a);
}
__device__ __forceinline__ ushort f2h(float x) {
  union { __half h; ushort u; } c; c.h = __float2half_rn(x); return c.u;
}
__device__ __forceinline__ __half2 u2h2(uint u) {
  union { uint uu; __half2 h; } c; c.uu = u; return c.h;
}
__device__ __forceinline__ uint h22u(__half2 h) {
  union { __half2 hh; uint u; } c; c.hh = h; return c.u;
}

// bijective XCD-chunked id mapping: 8 contiguous chunks, chunk i on XCD i
__device__ __forceinline__ int xcd_chunk(int bid, int nwg) {
  int xcd = bid & 7, off = bid >> 3;
  int q = nwg >> 3, r = nwg & 7;
  return (xcd < r ? xcd * (q + 1) : r * (q + 1) + (xcd - r) * q) + off;
}

// async global->LDS, 16B per lane; LDS dest is wave-uniform base + lane*16
__device__ __forceinline__ void gload16(const ushort* g, ushort* l) {
  __builtin_amdgcn_global_load_lds(
      (const __attribute__((address_space(1))) uint*)g,
      (__attribute__((address_space(3))) uint*)l, 16, 0, 0);
}

// ---------------------------------------------------------------------------
// Prelude: blocks 0..575 convert weights (fp32 [K][N] -> bf16 [Np][K] + padded
// biases); blocks 576.. run the fused LN3 (q build + qn/aq/af).
// ---------------------------------------------------------------------------
__global__ __launch_bounds__(256) void prelude_kernel(
    const float* __restrict__ Wv, const float* __restrict__ Woff,
    const float* __restrict__ Watt, const float* __restrict__ Wo,
    const float* __restrict__ fc1, const float* __restrict__ fc2,
    const float* __restrict__ boff, const float* __restrict__ batt,
    const float* __restrict__ fc1b,
    __hip_bfloat16* __restrict__ Wvt, __hip_bfloat16* __restrict__ Wot,
    __hip_bfloat16* __restrict__ Wofat, __hip_bfloat16* __restrict__ fc1t,
    __hip_bfloat16* __restrict__ fc2t, float* __restrict__ bofat,
    float* __restrict__ fc1bp,
    const float* __restrict__ query, const float* __restrict__ feat,
    const float* __restrict__ w1, const float* __restrict__ b1,
    const float* __restrict__ w2, const float* __restrict__ b2,
    const float* __restrict__ w3, const float* __restrict__ b3,
    const float* __restrict__ w4, const float* __restrict__ b4,
    __hip_bfloat16* __restrict__ qn, __hip_bfloat16* __restrict__ aq,
    __hip_bfloat16* __restrict__ af) {
  if (blockIdx.x < 576) {
    int id = blockIdx.x * 256 + threadIdx.x;
    int k = id % 384, n = id / 384;
    Wvt[(size_t)n * 384 + k] = __float2bfloat16(Wv[(size_t)k * 384 + n]);
    Wot[(size_t)n * 384 + k] = __float2bfloat16(Wo[(size_t)k * 384 + n]);
    if (n < 256) {
      float v = 0.f;
      if (n < 144) v = Woff[(size_t)k * 144 + n];
      else if (n < 216) v = Watt[(size_t)k * 72 + (n - 144)];
      Wofat[(size_t)n * 384 + k] = __float2bfloat16(v);
    }
    if (n < 128)
      fc1t[(size_t)n * 384 + k] = __float2bfloat16(n < 96 ? fc1[(size_t)k * 96 + n] : 0.f);
    if (k < 96)
      fc2t[(size_t)n * 96 + k] = __float2bfloat16(fc2[(size_t)k * 384 + n]);
    if (id < 256) bofat[id] = id < 144 ? boff[id] : (id < 216 ? batt[id - 144] : 0.f);
    if (id < 128) fc1bp[id] = id < 96 ? fc1b[id] : 0.f;
    return;
  }

  int wid = ((blockIdx.x - 576) * blockDim.x + threadIdx.x) >> 6;
  if (wid >= TOKS) return;
  int lane = threadIdx.x & 63;
  int bb = wid / NTOK;
  int nq = wid - bb * NTOK;

  float x[6];
  const float* qp = query + (size_t)wid * DIMC + lane;
#pragma unroll
  for (int i = 0; i < 6; ++i) x[i] = qp[64 * i];
  if (nq >= 9216 && nq < 11520) {
    const float* fp = feat + ((size_t)bb * 2304 + (nq - 9216)) * DIMC + lane;
#pragma unroll
    for (int i = 0; i < 6; ++i) x[i] += fp[64 * i];
  }

  float s = 0.f, ss = 0.f;
#pragma unroll
  for (int i = 0; i < 6; ++i) { s += x[i]; ss += x[i] * x[i]; }
  s = wave_reduce_add(s); ss = wave_reduce_add(ss);
  float mean = s * (1.f / DIMC);
  float rs = rsqrtf(ss * (1.f / DIMC) - mean * mean + 1e-6f);

  float qv[6], fv[6];
  __hip_bfloat16* qnp = qn + (size_t)wid * DIMC + lane;
#pragma unroll
  for (int i = 0; i < 6; ++i) {
    int e = lane + 64 * i;
    float xh = (x[i] - mean) * rs;
    qv[i] = xh * w1[e] + b1[e];
    fv[i] = xh * w2[e] + b2[e];
    qnp[64 * i] = __float2bfloat16(qv[i]);
  }

  s = 0.f; ss = 0.f;
#pragma unroll
  for (int i = 0; i < 6; ++i) { s += qv[i]; ss += qv[i] * qv[i]; }
  s = wave_reduce_add(s); ss = wave_reduce_add(ss);
  float m2 = s * (1.f / DIMC);
  float rs2 = rsqrtf(ss * (1.f / DIMC) - m2 * m2 + 1e-6f);
  __hip_bfloat16* aqp = aq + (size_t)wid * DIMC + lane;
#pragma unroll
  for (int i = 0; i < 6; ++i) {
    int e = lane + 64 * i;
    aqp[64 * i] = __float2bfloat16((qv[i] - m2) * rs2 * w3[e] + b3[e]);
  }

  s = 0.f; ss = 0.f;
#pragma unroll
  for (int i = 0; i < 6; ++i) { s += fv[i]; ss += fv[i] * fv[i]; }
  s = wave_reduce_add(s); ss = wave_reduce_add(ss);
  float m3 = s * (1.f / DIMC);
  float rs3 = rsqrtf(ss * (1.f / DIMC) - m3 * m3 + 1e-6f);
  __hip_bfloat16* afp = af + (size_t)wid * DIMC + lane;
#pragma unroll
  for (int i = 0; i < 6; ++i) {
    int e = lane + 64 * i;
    afp[64 * i] = __float2bfloat16((fv[i] - m3) * rs3 * w4[e] + b4[e]);
  }
}

// ---------------------------------------------------------------------------
// ffn_norm: fp32 in -> bf16 out. Vectorized (dwordx2 loads, packed stores).
// ---------------------------------------------------------------------------
__global__ __launch_bounds__(256) void ln_kernel(
    const float* __restrict__ x, const float* __restrict__ w,
    const float* __restrict__ b, __hip_bfloat16* __restrict__ y) {
  int wid = (blockIdx.x * blockDim.x + threadIdx.x) >> 6;
  if (wid >= TOKS) return;
  int lane = threadIdx.x & 63;
  int c0 = lane * 2;

  float2 v[3];
  const float* xp = x + (size_t)wid * DIMC;
#pragma unroll
  for (int i = 0; i < 3; ++i) v[i] = *(const float2*)&xp[c0 + 128 * i];

  float s = 0.f, ss = 0.f;
#pragma unroll
  for (int i = 0; i < 3; ++i) {
    s += v[i].x + v[i].y;
    ss += v[i].x * v[i].x + v[i].y * v[i].y;
  }
  s = wave_reduce_add(s); ss = wave_reduce_add(ss);
  float mean = s * (1.f / DIMC);
  float rs = rsqrtf(ss * (1.f / DIMC) - mean * mean + 1e-6f);

  uint* yp = (uint*)((char*)y + (size_t)wid * DIMC * 2);
#pragma unroll
  for (int i = 0; i < 3; ++i) {
    int e = c0 + 128 * i;
    float2 wv = *(const float2*)&w[e];
    float2 bv = *(const float2*)&b[e];
    float a = (v[i].x - mean) * rs * wv.x + bv.x;
    float c = (v[i].y - mean) * rs * wv.y + bv.y;
    yp[lane + 64 * i] = pk2bf(a, c);
  }
}

// ---------------------------------------------------------------------------
// bf16 MFMA GEMM: 128x128 tile, 4 waves, 2-phase double-buffered
// global_load_lds pipeline, pre-swizzled source, XCD-chunked tile mapping.
// ---------------------------------------------------------------------------
template <int EPI, int OUTBF16>
__global__ __launch_bounds__(256) void gemm_mfma(
    const __hip_bfloat16* __restrict__ A, const __hip_bfloat16* __restrict__ Wt,
    const float* __restrict__ bias, const void* __restrict__ Rv,
    void* __restrict__ Cv, int K, int Np, int ntx) {
  __shared__ __align__(16) ushort As[2 * 128 * 32];
  __shared__ __align__(16) ushort Bs[2 * 128 * 32];
  const int tid = threadIdx.x;
  const int tile = xcd_chunk(blockIdx.x, gridDim.x);
  const int tx = tile % ntx, ty = tile / ntx;
  const int m0 = ty * 128, n0 = tx * 128;

  const int lane = tid & 63, wv = tid >> 6;
  const int wm = (wv >> 1) * 64, wn = (wv & 1) * 64;
  const int rl = lane & 15, kb = lane >> 4;

  const int c0 = wv * 64 + lane;
  const int c1 = c0 + 256;
  const int r0c = c0 >> 2, b0 = (c0 & 3) ^ (r0c & 3);
  const int r1c = c1 >> 2, b1 = (c1 & 3) ^ (r1c & 3);
  const ushort* gA0 = (const ushort*)A + (size_t)(m0 + r0c) * K + b0 * 8;
  const ushort* gA1 = (const ushort*)A + (size_t)(m0 + r1c) * K + b1 * 8;
  const ushort* gB0 = (const ushort*)Wt + (size_t)(n0 + r0c) * K + b0 * 8;
  const ushort* gB1 = (const ushort*)Wt + (size_t)(n0 + r1c) * K + b1 * 8;
  ushort* lA0 = &As[(size_t)wv * 512];
  ushort* lA1 = &As[(size_t)wv * 512 + 2048];
  ushort* lB0 = &Bs[(size_t)wv * 512];
  ushort* lB1 = &Bs[(size_t)wv * 512 + 2048];

  f32x4 acc[4][4] = {};
  const int nt = K >> 5;

  gload16(gA0, lA0);
  gload16(gA1, lA1);
  gload16(gB0, lB0);
  gload16(gB1, lB1);
  __syncthreads();

  for (int t = 0; t < nt; ++t) {
    const int cb = (t & 1) << 12;
    const int nb = 4096 - cb;
    if (t + 1 < nt) {
      const int k1 = (t + 1) << 5;
      gload16(gA0 + k1, lA0 + nb);
      gload16(gA1 + k1, lA1 + nb);
      gload16(gB0 + k1, lB0 + nb);
      gload16(gB1 + k1, lB1 + nb);
    }
    bf16x8 avf[4], bvf[4];
#pragma unroll
    for (int i = 0; i < 4; ++i) {
      int ra = wm + i * 16 + rl;
      avf[i] = *(const bf16x8*)&As[cb + ra * 32 + ((kb ^ (ra & 3)) << 3)];
      int rb = wn + i * 16 + rl;
      bvf[i] = *(const bf16x8*)&Bs[cb + rb * 32 + ((kb ^ (rb & 3)) << 3)];
    }
#pragma unroll
    for (int i = 0; i < 4; ++i)
#pragma unroll
      for (int j = 0; j < 4; ++j)
        acc[i][j] = __builtin_amdgcn_mfma_f32_16x16x32_bf16(avf[i], bvf[j],
                                                            acc[i][j], 0, 0, 0);
    __syncthreads();
  }

#pragma unroll
  for (int i = 0; i < 4; ++i) {
#pragma unroll
    for (int j = 0; j < 4; ++j) {
      int col = n0 + wn + j * 16 + rl;
      float bsv = bias[col];
#pragma unroll
      for (int rr = 0; rr < 4; ++rr) {
        int row = m0 + wm + i * 16 + kb * 4 + rr;
        size_t o = (size_t)row * Np + col;
        float v = acc[i][j][rr] + bsv;
        if (EPI == 1) v += __bfloat162float(((const __hip_bfloat16*)Rv)[o]);
        if (EPI == 2) v += ((const float*)Cv)[o];
        if (OUTBF16) ((__hip_bfloat16*)Cv)[o] = __float2bfloat16(v);
        else ((float*)Cv)[o] = v;
      }
    }
  }
}

// ---------------------------------------------------------------------------
// Dual GEMM: region 1 (blocks 0..566): val = af @ Wvt + bv (F16 out,
// Np=384, ntx=3). Region 2 (blocks 567..944): offatt = aq @ Wofat + bofat
// (f32 out, Np=256, ntx=2).
// ---------------------------------------------------------------------------
__global__ __launch_bounds__(256) void gemm_dual(
    const __hip_bfloat16* __restrict__ A1, const __hip_bfloat16* __restrict__ W1,
    const float* __restrict__ bias1, void* __restrict__ C1,
    const __hip_bfloat16* __restrict__ A2, const __hip_bfloat16* __restrict__ W2,
    const float* __restrict__ bias2, void* __restrict__ C2) {
  __shared__ __align__(16) ushort As[2 * 128 * 32];
  __shared__ __align__(16) ushort Bs[2 * 128 * 32];
  const int tid = threadIdx.x;
  const int gbid = blockIdx.x;
  const bool r2 = gbid >= 567;
  const __hip_bfloat16* A = r2 ? A2 : A1;
  const __hip_bfloat16* Wt = r2 ? W2 : W1;
  const float* bias = r2 ? bias2 : bias1;
  void* Cv = r2 ? C2 : C1;
  const int Np = r2 ? 256 : 384, ntx = r2 ? 2 : 3;
  const int lbid = r2 ? gbid - 567 : gbid;
  const int lnwg = r2 ? 378 : 567;
  const int K = 384;

  const int tile = xcd_chunk(lbid, lnwg);
  const int tx = tile % ntx, ty = tile / ntx;
  const int m0 = ty * 128, n0 = tx * 128;

  const int lane = tid & 63, wv = tid >> 6;
  const int wm = (wv >> 1) * 64, wn = (wv & 1) * 64;
  const int rl = lane & 15, kb = lane >> 4;

  const int c0 = wv * 64 + lane;
  const int c1 = c0 + 256;
  const int r0c = c0 >> 2, b0 = (c0 & 3) ^ (r0c & 3);
  const int r1c = c1 >> 2, b1 = (c1 & 3) ^ (r1c & 3);
  const ushort* gA0 = (const ushort*)A + (size_t)(m0 + r0c) * K + b0 * 8;
  const ushort* gA1 = (const ushort*)A + (size_t)(m0 + r1c) * K + b1 * 8;
  const ushort* gB0 = (const ushort*)Wt + (size_t)(n0 + r0c) * K + b0 * 8;
  const ushort* gB1 = (const ushort*)Wt + (size_t)(n0 + r1c) * K + b1 * 8;
  ushort* lA0 = &As[(size_t)wv * 512];
  ushort* lA1 = &As[(size_t)wv * 512 + 2048];
  ushort* lB0 = &Bs[(size_t)wv * 512];
  ushort* lB1 = &Bs[(size_t)wv * 512 + 2048];

  f32x4 acc[4][4] = {};
  const int nt = K >> 5;

  gload16(gA0, lA0);
  gload16(gA1, lA1);
  gload16(gB0, lB0);
  gload16(gB1, lB1);
  __syncthreads();

  for (int t = 0; t < nt; ++t) {
    const int cb = (t & 1) << 12;
    const int nb = 4096 - cb;
    if (t + 1 < nt) {
      const int k1 = (t + 1) << 5;
      gload16(gA0 + k1, lA0 + nb);
      gload16(gA1 + k1, lA1 + nb);
      gload16(gB0 + k1, lB0 + nb);
      gload16(gB1 + k1, lB1 + nb);
    }
    bf16x8 avf[4], bvf[4];
#pragma unroll
    for (int i = 0; i < 4; ++i) {
      int ra = wm + i * 16 + rl;
      avf[i] = *(const bf16x8*)&As[cb + ra * 32 + ((kb ^ (ra & 3)) << 3)];
      int rb = wn + i * 16 + rl;
      bvf[i] = *(const bf16x8*)&Bs[cb + rb * 32 + ((kb ^ (rb & 3)) << 3)];
    }
#pragma unroll
    for (int i = 0; i < 4; ++i)
#pragma unroll
      for (int j = 0; j < 4; ++j)
        acc[i][j] = __builtin_amdgcn_mfma_f32_16x16x32_bf16(avf[i], bvf[j],
                                                            acc[i][j], 0, 0, 0);
    __syncthreads();
  }

#pragma unroll
  for (int i = 0; i < 4; ++i) {
#pragma unroll
    for (int j = 0; j < 4; ++j) {
      int col = n0 + wn + j * 16 + rl;
      float bsv = bias[col];
#pragma unroll
      for (int rr = 0; rr < 4; ++rr) {
        int row = m0 + wm + i * 16 + kb * 4 + rr;
        size_t o = (size_t)row * Np + col;
        float v = acc[i][j][rr] + bsv;
        if (!r2) ((__half*)Cv)[o] = __float2half_rn(v);
        else ((float*)Cv)[o] = v;
      }
    }
  }
}

// ---------------------------------------------------------------------------
// Sampling phase 1 (dense): one THREAD per (t,h,l,p); emits 4 tap-corner
// records rec = (F16(tap_weight) << 16) | (y*Wl + x). XCD-chunked.
// ---------------------------------------------------------------------------
__global__ __launch_bounds__(256) void msdeform_prep(
    const float* __restrict__ offatt, uint* __restrict__ taps) {
  int tile = xcd_chunk(blockIdx.x, gridDim.x);
  int id = tile * 256 + (int)threadIdx.x;
  if (id >= TOKS * 72) return;
  int t = id / 72, r = id - t * 72;
  int h = r / 12, lp = r - h * 12;
  int l = lp >> 2;
  int nq = t % NTOK;

  int pos, Hq, Wq;
  if (nq < 9216)       { pos = nq;         Hq = 96; Wq = 96; }
  else if (nq < 11520) { pos = nq - 9216;  Hq = 48; Wq = 48; }
  else                 { pos = nq - 11520; Hq = 24; Wq = 24; }
  int iq = pos / Wq, jq = pos - iq * Wq;
  float refx = (jq + 0.5f) / (float)Wq;
  float refy = (iq + 0.5f) / (float)Hq;

  const float* lg = offatt + (size_t)t * 256 + 144 + h * 12;
  float mx = -1e30f;
#pragma unroll
  for (int i = 0; i < 12; ++i) mx = fmaxf(mx, lg[i]);
  float sden = 0.f;
#pragma unroll
  for (int i = 0; i < 12; ++i) sden += __expf(lg[i] - mx);
  float aw = __expf(lg[lp] - mx) / sden;

  float ox = offatt[(size_t)t * 256 + h * 24 + lp * 2 + 0];
  float oy = offatt[(size_t)t * 256 + h * 24 + lp * 2 + 1];

  int Wl = 96 >> l;

  float xx = refx * (float)Wl + ox - 0.5f;
  float yy = refy * (float)Wl + oy - 0.5f;
  float x0f = floorf(xx), y0f = floorf(yy);
  int x0 = (int)x0f, y0 = (int)y0f;
  float wx = xx - x0f, wy = yy - y0f;

  bool vx0 = (x0 >= 0) & (x0 < Wl), vx1 = (x0 + 1 >= 0) & (x0 + 1 < Wl);
  bool vy0 = (y0 >= 0) & (y0 < Wl), vy1 = (y0 + 1 >= 0) & (y0 + 1 < Wl);
  int x0c = min(max(x0, 0), Wl - 1), x1c = min(max(x0 + 1, 0), Wl - 1);
  int y0c = min(max(y0, 0), Wl - 1), y1c = min(max(y0 + 1, 0), Wl - 1);

  float w00 = (vy0 && vx0) ? aw * (1.f - wx) * (1.f - wy) : 0.f;
  float w01 = (vy0 && vx1) ? aw * wx * (1.f - wy) : 0.f;
  float w10 = (vy1 && vx0) ? aw * (1.f - wx) * wy : 0.f;
  float w11 = (vy1 && vx1) ? aw * wx * wy : 0.f;

  uint4 rec;
  rec.x = ((uint)f2h(w00) << 16) | (uint)(y0c * Wl + x0c);
  rec.y = ((uint)f2h(w01) << 16) | (uint)(y0c * Wl + x1c);
  rec.z = ((uint)f2h(w10) << 16) | (uint)(y1c * Wl + x0c);
  rec.w = ((uint)f2h(w11) << 16) | (uint)(y1c * Wl + x1c);
  *(uint4*)&taps[((size_t)(t * NHEADS + h)) * 48 + lp * 4] = rec;
}

// ---------------------------------------------------------------------------
// Sampling phase 2: one wave per (t,h). 8-lane groups; iteration i loads
// 8 tap records (dword) and 8x128B of F16 value via dwordx4. Packed-f16
// math: 4x v_pk_fma_f16 per tap (no unpack). Packed shuffle reduce.
// XCD-chunked blocks.
// ---------------------------------------------------------------------------
__global__ __launch_bounds__(256) void msdeform_gather(
    const __half* __restrict__ value, const uint* __restrict__ taps,
    __hip_bfloat16* __restrict__ samp) {
  int swz = xcd_chunk(blockIdx.x, gridDim.x);
  int wid = __builtin_amdgcn_readfirstlane(swz * 4 + ((int)threadIdx.x >> 6));
  int lane = threadIdx.x & 63;
  int g = lane >> 3, sub = lane & 7;
  int sub16 = sub * 16;

  int t = wid / NHEADS;
  int h = wid - t * NHEADS;
  int b = t / NTOK;

  const char* vb = (const char*)value + ((size_t)(b * NTOK) * DIMC + h * CHD) * 2;
  const char* vbl[3] = {vb, vb + 9216 * DIMC * 2, vb + 11520 * DIMC * 2};

  const uint* tp = taps + (size_t)wid * 48 + g;

  __half2 acc[4];
#pragma unroll
  for (int r = 0; r < 4; ++r) acc[r] = u2h2(0u);

#pragma unroll
  for (int i = 0; i < 6; ++i) {
    uint rec = tp[i * 8];
    __half2 w2 = u2h2((rec & 0xffff0000u) | (rec >> 16));
    uint off = (rec & 0x3fffu) * (uint)(DIMC * 2) + (uint)sub16;
    uint4 d = *(const uint4*)(vbl[i >> 1] + off);
    acc[0] = __hfma2(u2h2(d.x), w2, acc[0]);
    acc[1] = __hfma2(u2h2(d.y), w2, acc[1]);
    acc[2] = __hfma2(u2h2(d.z), w2, acc[2]);
    acc[3] = __hfma2(u2h2(d.w), w2, acc[3]);
  }

#pragma unroll
  for (int r = 0; r < 4; ++r) {
    acc[r] = __hadd2(acc[r], u2h2(__shfl_xor(h22u(acc[r]), 8, 64)));
    acc[r] = __hadd2(acc[r], u2h2(__shfl_xor(h22u(acc[r]), 16, 64)));
    acc[r] = __hadd2(acc[r], u2h2(__shfl_xor(h22u(acc[r]), 32, 64)));
  }

  if (lane < 8) {
    float2 f0 = __half22float2(acc[0]);
    float2 f1 = __half22float2(acc[1]);
    float2 f2 = __half22float2(acc[2]);
    float2 f3 = __half22float2(acc[3]);
    uint4 o;
    o.x = pk2bf(f0.x, f0.y);
    o.y = pk2bf(f1.x, f1.y);
    o.z = pk2bf(f2.x, f2.y);
    o.w = pk2bf(f3.x, f3.y);
    *(uint4*)((char*)samp + (size_t)wid * 128 + sub16) = o;
  }
}

// ---------------------------------------------------------------------------
// Depthwise 3x3 + bias + exact GELU, 8 channels/thread (uint4 taps).
// x bf16 [T][128] (padded), y bf16 [T][96].
// ---------------------------------------------------------------------------
__global__ __launch_bounds__(256) void dwconv_gelu(
    const __hip_bfloat16* __restrict__ x, const float* __restrict__ w,
    const float* __restrict__ bias, __hip_bfloat16* __restrict__ y) {
  int id = blockIdx.x * blockDim.x + threadIdx.x;
  if (id >= TOKS * 12) return;
  int g = id % 12;
  int tn = id / 12;
  int ch0 = g * 8;
  int b = tn / NTOK, nq = tn - b * NTOK;

  int pos, Hl, Wl, st;
  if (nq < 9216)       { pos = nq;         Hl = 96; Wl = 96; st = 0; }
  else if (nq < 11520) { pos = nq - 9216;  Hl = 48; Wl = 48; st = 9216; }
  else                 { pos = nq - 11520; Hl = 24; Wl = 24; st = 11520; }
  int i = pos / Wl, j = pos - i * Wl;

  float acc[8];
#pragma unroll
  for (int c = 0; c < 8; ++c) acc[c] = bias[ch0 + c];
#pragma unroll
  for (int di = 0; di < 3; ++di) {
#pragma unroll
    for (int dj = 0; dj < 3; ++dj) {
      int ii = i + di - 1, jj = j + dj - 1;
      if (ii >= 0 && ii < Hl && jj >= 0 && jj < Wl) {
        uint4 d = *(const uint4*)&x[((size_t)(b * NTOK + st + ii * Wl + jj)) * 128 + ch0];
        const float* wr = &w[(di * 3 + dj) * 96 + ch0];
        f32x4 w0 = *(const f32x4*)&wr[0];
        f32x4 w1 = *(const f32x4*)&wr[4];
        acc[0] = fmaf(bf_lo(d.x), w0[0], acc[0]);
        acc[1] = fmaf(bf_hi(d.x), w0[1], acc[1]);
        acc[2] = fmaf(bf_lo(d.y), w0[2], acc[2]);
        acc[3] = fmaf(bf_hi(d.y), w0[3], acc[3]);
        acc[4] = fmaf(bf_lo(d.z), w1[0], acc[4]);
        acc[5] = fmaf(bf_hi(d.z), w1[1], acc[5]);
        acc[6] = fmaf(bf_lo(d.w), w1[2], acc[6]);
        acc[7] = fmaf(bf_hi(d.w), w1[3], acc[7]);
      }
    }
  }
  float gl[8];
#pragma unroll
  for (int c = 0; c < 8; ++c)
    gl[c] = 0.5f * acc[c] * (1.f + erff(acc[c] * 0.70710678f));
  uint4 o;
  o.x = pk2bf(gl[0], gl[1]);
  o.y = pk2bf(gl[2], gl[3]);
  o.z = pk2bf(gl[4], gl[5]);
  o.w = pk2bf(gl[6], gl[7]);
  *(uint4*)((char*)y + (size_t)tn * 192 + ch0 * 2) = o;
}

// ---------------------------------------------------------------------------
extern "C" void kernel_launch(void* const* d_in, const int* in_sizes, int n_in,
                              void* d_out, int out_size, void* d_ws, size_t ws_size,
                              hipStream_t stream) {
  const float* query = (const float*)d_in[0];
  const float* feat   = (const float*)d_in[2];
  const float* cti_qw = (const float*)d_in[7];
  const float* cti_qb = (const float*)d_in[8];
  const float* cti_fw = (const float*)d_in[9];
  const float* cti_fb = (const float*)d_in[10];
  const float* cf_qw  = (const float*)d_in[11];
  const float* cf_qb  = (const float*)d_in[12];
  const float* cf_fw  = (const float*)d_in[13];
  const float* cf_fb  = (const float*)d_in[14];
  const float* Wv     = (const float*)d_in[15];
  const float* bv     = (const float*)d_in[16];
  const float* Woff   = (const float*)d_in[17];
  const float* boff   = (const float*)d_in[18];
  const float* Watt   = (const float*)d_in[19];
  const float* batt   = (const float*)d_in[20];
  const float* Wo     = (const float*)d_in[21];
  const float* bo     = (const float*)d_in[22];
  const float* ffw    = (const float*)d_in[23];
  const float* ffb    = (const float*)d_in[24];
  const float* fc1w   = (const float*)d_in[25];
  const float* fc1b   = (const float*)d_in[26];
  const float* dww    = (const float*)d_in[27];
  const float* dwb    = (const float*)d_in[28];
  const float* fc2w   = (const float*)d_in[29];
  const float* fc2b   = (const float*)d_in[30];
  float* out = (float*)d_out;

  char* ws = (char*)d_ws;
  __hip_bfloat16* qn  = (__hip_bfloat16*)ws;                // T*384 bf16
  __hip_bfloat16* aq  = (__hip_bfloat16*)(ws + 37158912);   // T*384 bf16
  __hip_bfloat16* af  = (__hip_bfloat16*)(ws + 55738368);   // T*384 bf16
  __half* val         = (__half*)(ws + 74317824);           // T*384 f16
  float* offatt       = (float*)(ws + 92897280);            // T*256 f32
  char* wbase = ws + 117669888;
  __hip_bfloat16* Wvt   = (__hip_bfloat16*)(wbase + 0);
  __hip_bfloat16* Wot   = (__hip_bfloat16*)(wbase + 589824);
  __hip_bfloat16* Wofat = (__hip_bfloat16*)(wbase + 1179648);
  __hip_bfloat16* fc1t  = (__hip_bfloat16*)(wbase + 1376256);
  __hip_bfloat16* fc2t  = (__hip_bfloat16*)(wbase + 1474560);
  float* bofat          = (float*)(wbase + 1548288);
  float* fc1bp          = (float*)(wbase + 1549312);
  // sampling tap table (tail region): T*6*48 uints = 27.87MB
  uint* taps = (uint*)(ws + 119220224);
  // reuse regions
  __hip_bfloat16* samp = af;
  __hip_bfloat16* lnf  = aq;
  __hip_bfloat16* h1   = (__hip_bfloat16*)offatt;           // T*128 bf16
  __hip_bfloat16* h2   = (__hip_bfloat16*)(ws + 92897280 + 6193152); // T*96 bf16

  dim3 blk(256);

  // convert weights (blocks 0..575) + fused LN3 (blocks 576..)
  prelude_kernel<<<576 + TOKS / 4, blk, 0, stream>>>(
      Wv, Woff, Watt, Wo, fc1w, fc2w, boff, batt, fc1b, Wvt, Wot, Wofat, fc1t,
      fc2t, bofat, fc1bp, query, feat, cti_qw, cti_qb, cti_fw, cti_fb, cf_qw,
      cf_qb, cf_fw, cf_fb, qn, aq, af);

  // val(f16) = af @ Wvt + bv  ||  offatt = aq @ Wofat + bofat (f32)
  gemm_dual<<<945, blk, 0, stream>>>(af, Wvt, bv, val, aq, Wofat, bofat, offatt);

  // dense prep, then packed-f16 wide-load gather
  msdeform_prep<<<(TOKS * 72) / 256, blk, 0, stream>>>(offatt, taps);
  msdeform_gather<<<(TOKS * NHEADS) / 4, blk, 0, stream>>>(val, taps, samp);

  // out = samp @ Wout + bout + qn(bf16)  (f32 out)
  gemm_mfma<1, 0><<<567, blk, 0, stream>>>(samp, Wot, bo, qn, out, 384, 384, 3);

  ln_kernel<<<TOKS / 4, blk, 0, stream>>>(out, ffw, ffb, lnf);
  // h1 = lnf @ fc1 -> bf16 [T][128]
  gemm_mfma<0, 1><<<189, blk, 0, stream>>>(lnf, fc1t, fc1bp, nullptr, h1, 384, 128, 1);
  dwconv_gelu<<<(TOKS * 12 + 255) / 256, blk, 0, stream>>>(h1, dww, dwb, h2);
  // out += h2 @ fc2 + fc2_b  (K=96)
  gemm_mfma<2, 0><<<567, blk, 0, stream>>>(h2, fc2t, fc2b, nullptr, out, 96, 384, 3);
}